// Round 2
// baseline (652.537 us; speedup 1.0000x reference)
//
#include <hip/hip_runtime.h>
#include <hip/hip_bf16.h>
#include <hip/hip_fp16.h>

#define N_NODES 50000
#define N_EDGES 800000

typedef unsigned short ushort_t;
typedef unsigned int uint_t;
typedef __attribute__((ext_vector_type(8))) short short8;
typedef __attribute__((ext_vector_type(4))) float f32x4;

// ---------------- bf16 split helpers ----------------
__device__ inline ushort_t bf16_rne(float x) {
    uint_t u = __float_as_uint(x);
    uint_t r = (u + 0x7fffu + ((u >> 16) & 1u)) >> 16;
    return (ushort_t)r;
}
__device__ inline void split1(float x, ushort_t& h, ushort_t& l) {
    ushort_t hh = bf16_rne(x);
    float fh = __uint_as_float((uint_t)hh << 16);
    h = hh;
    l = bf16_rne(x - fh);
}

// ---------------- async global->LDS (16B per lane, wave-uniform LDS base) ----
__device__ inline void gl_lds16(const void* g, void* l) {
    __builtin_amdgcn_global_load_lds(
        (const __attribute__((address_space(1))) unsigned int*)g,
        (__attribute__((address_space(3))) unsigned int*)l, 16, 0, 0);
}

// ---------------- degree count ----------------
__global__ void count_deg_k(const int* __restrict__ src, const int* __restrict__ dst,
                            int n_edges, int* __restrict__ deg_out, int* __restrict__ deg_in) {
    int i = blockIdx.x * blockDim.x + threadIdx.x;
    if (i < n_edges) {
        atomicAdd(&deg_out[src[i]], 1);
        atomicAdd(&deg_in[dst[i]], 1);
    }
}

// ---------------- norms ----------------
__global__ void norm_k(const int* __restrict__ deg_out, const int* __restrict__ deg_in,
                       float* __restrict__ ns, float* __restrict__ nd, int n) {
    int i = blockIdx.x * blockDim.x + threadIdx.x;
    if (i < n) {
        ns[i] = 1.0f / sqrtf((float)max(deg_out[i], 1));
        nd[i] = 1.0f / sqrtf((float)max(deg_in[i], 1));
    }
}

// ---------------- exclusive scan (single block, shfl-based) ----------------
__global__ void scan_k(const int* __restrict__ deg, int* __restrict__ row_start,
                       int* __restrict__ cursor, int n) {
    __shared__ int wexcl[16];
    __shared__ int chunk_total;
    __shared__ int carry_s;
    const int tid = threadIdx.x;
    const int lane = tid & 63, wid = tid >> 6;
    if (tid == 0) carry_s = 0;
    for (int base = 0; base < n; base += 1024) {
        int i = base + tid;
        int v = (i < n) ? deg[i] : 0;
        // inclusive wave scan
        int x = v;
#pragma unroll
        for (int off = 1; off < 64; off <<= 1) {
            int y = __shfl_up(x, off, 64);
            if (lane >= off) x += y;
        }
        __syncthreads();  // protect wexcl reuse across chunks; orders carry_s update
        if (lane == 63) wexcl[wid] = x;
        __syncthreads();
        if (wid == 0) {
            int tv = (lane < 16) ? wexcl[lane] : 0;
            int xs = tv;
#pragma unroll
            for (int off = 1; off < 16; off <<= 1) {
                int y = __shfl_up(xs, off, 64);
                if (lane >= off) xs += y;
            }
            if (lane < 16) wexcl[lane] = xs - tv;  // exclusive wave offset
            if (lane == 15) chunk_total = xs;
        }
        __syncthreads();
        int carry = carry_s;
        if (i < n) {
            int o = carry + wexcl[wid] + x - v;
            row_start[i] = o;
            cursor[i] = o;
        }
        __syncthreads();  // all reads of carry_s done
        if (tid == 0) carry_s = carry + chunk_total;
    }
    if (tid == 0) row_start[n] = carry_s;
}

// ---------------- CSR fill ----------------
__global__ void fill_csr_k(const int* __restrict__ src, const int* __restrict__ dst,
                           int n_edges, int* __restrict__ cursor, int* __restrict__ edge_src) {
    int i = blockIdx.x * blockDim.x + threadIdx.x;
    if (i < n_edges) {
        int pos = atomicAdd(&cursor[dst[i]], 1);
        edge_src[pos] = src[i];
    }
}

// ---------------- split+transpose all 4 weights in one launch ----------------
__global__ void split_weights_k(const float* __restrict__ W0, const float* __restrict__ W1,
                                const float* __restrict__ W2, const float* __restrict__ W3,
                                ushort_t* __restrict__ W0h, ushort_t* __restrict__ W0l,
                                ushort_t* __restrict__ W1h, ushort_t* __restrict__ W1l,
                                ushort_t* __restrict__ W2h, ushort_t* __restrict__ W2l,
                                ushort_t* __restrict__ W3h, ushort_t* __restrict__ W3l) {
    const int s0 = 512 * 256, s1 = s0 + 256 * 256, s2 = s1 + 256 * 128, s3 = s2 + 128 * 64;
    int idx = blockIdx.x * blockDim.x + threadIdx.x;
    const float* W;
    ushort_t *H, *L;
    int K, N, local;
    if (idx < s0) { W = W0; H = W0h; L = W0l; K = 512; N = 256; local = idx; }
    else if (idx < s1) { W = W1; H = W1h; L = W1l; K = 256; N = 256; local = idx - s0; }
    else if (idx < s2) { W = W2; H = W2h; L = W2l; K = 256; N = 128; local = idx - s1; }
    else if (idx < s3) { W = W3; H = W3h; L = W3l; K = 128; N = 64; local = idx - s2; }
    else return;
    int n = local / K;
    int k = local - n * K;
    split1(W[(size_t)k * N + n], H[local], L[local]);
}

// ---------------- MFMA GEMM: C[M,N] = fp16( ns[row] * (A @ W) ), bf16x2 3-pass ----
// BM=64, BN = full N (256/128/64), grid.y = 1 -> each A row loaded/split ONCE.
// 256 threads = 4 waves, all along N: TM=4, TN=BN/64.
// ASRC=0: A as hi/lo bf16 planes [M][K], staged via global_load_lds (async DMA).
// ASRC=1: A fp32 [M][K], split inline through registers (done once per row now).
// W as transposed hi/lo planes [N][K], staged via global_load_lds.
// LDS layout linear in chunk order: chunk c (row c>>2, k-octet c&3) at bytes [16c,16c+16).
template <int BN, int ASRC>  // BN: 256, 128 or 64
__global__ __launch_bounds__(256) void gemm_mfma_k(
    const float* __restrict__ Af,
    const ushort_t* __restrict__ Ahi, const ushort_t* __restrict__ Alo,
    const ushort_t* __restrict__ Bhi, const ushort_t* __restrict__ Blo,
    __half* __restrict__ C, int M, int K, int N, const float* __restrict__ ns) {
    constexpr int BM = 64, BK = 32;
    constexpr int TM = 4;            // 64/16
    constexpr int TN = BN / 64;      // 4 waves span BN
    __shared__ __attribute__((aligned(16))) ushort_t Ah[BM * BK];
    __shared__ __attribute__((aligned(16))) ushort_t Al[BM * BK];
    __shared__ __attribute__((aligned(16))) ushort_t Bh[BN * BK];
    __shared__ __attribute__((aligned(16))) ushort_t Bl[BN * BK];
    const int t = threadIdx.x;
    const int wave = t >> 6, lane = t & 63;
    const int quad = lane >> 4, l16 = lane & 15;
    const int m0 = blockIdx.x * BM, n0 = blockIdx.y * BN;
    const int wcol = wave * (TN * 16);

    f32x4 acc[TM][TN];
#pragma unroll
    for (int mi = 0; mi < TM; ++mi)
#pragma unroll
        for (int ni = 0; ni < TN; ++ni) acc[mi][ni] = (f32x4){0.f, 0.f, 0.f, 0.f};

    for (int k0 = 0; k0 < K; k0 += BK) {
        // ---- stage A (BM*4 = 256 chunks)
        if (ASRC == 0) {
            // async DMA: one call-group per wave, wave-uniform LDS base
            int c = wave * 64 + lane;  // chunk 0..255
            int r = c >> 2, q = c & 3;
            int gr = m0 + r;
            if (gr >= M) gr = M - 1;
            size_t goff = (size_t)gr * K + k0 + q * 8;
            gl_lds16(Ahi + goff, &Ah[wave * 512]);
            gl_lds16(Alo + goff, &Al[wave * 512]);
        } else {
            // fp32 -> bf16 hi/lo split through registers (transform can't ride DMA)
            int c = t;  // 1 chunk per thread
            int r = c >> 2, q = c & 3;
            int gr = m0 + r;
            if (gr >= M) gr = M - 1;
            const float* ap = Af + (size_t)gr * K + k0 + q * 8;
            float4 v0 = *(const float4*)ap;
            float4 v1 = *(const float4*)(ap + 4);
            float vv[8] = {v0.x, v0.y, v0.z, v0.w, v1.x, v1.y, v1.z, v1.w};
            short8 hh, ll;
#pragma unroll
            for (int ee = 0; ee < 8; ++ee) {
                ushort_t h, l;
                split1(vv[ee], h, l);
                hh[ee] = (short)h;
                ll[ee] = (short)l;
            }
            *(short8*)&Ah[c * 8] = hh;
            *(short8*)&Al[c * 8] = ll;
        }
        // ---- stage B (always async DMA): BN*4 chunks per plane
#pragma unroll
        for (int j = 0; j < BN / 64; ++j) {
            int cg = wave * (BN / 64) + j;
            int c = cg * 64 + lane;
            int r = c >> 2, q = c & 3;
            size_t goff = (size_t)(n0 + r) * K + k0 + q * 8;
            gl_lds16(Bhi + goff, &Bh[cg * 512]);
            gl_lds16(Blo + goff, &Bl[cg * 512]);
        }
        __syncthreads();
        // ---- fragments: A[m=l16][k=quad*8+j], B[k=quad*8+j][n=l16]
        short8 afh[TM], afl[TM], bfh[TN], bfl[TN];
#pragma unroll
        for (int mi = 0; mi < TM; ++mi) {
            int m = mi * 16 + l16;
            afh[mi] = *(const short8*)&Ah[m * BK + quad * 8];
            afl[mi] = *(const short8*)&Al[m * BK + quad * 8];
        }
#pragma unroll
        for (int ni = 0; ni < TN; ++ni) {
            int n = wcol + ni * 16 + l16;
            bfh[ni] = *(const short8*)&Bh[n * BK + quad * 8];
            bfl[ni] = *(const short8*)&Bl[n * BK + quad * 8];
        }
#pragma unroll
        for (int mi = 0; mi < TM; ++mi)
#pragma unroll
            for (int ni = 0; ni < TN; ++ni) {
                acc[mi][ni] = __builtin_amdgcn_mfma_f32_16x16x32_bf16(afh[mi], bfh[ni],
                                                                      acc[mi][ni], 0, 0, 0);
                acc[mi][ni] = __builtin_amdgcn_mfma_f32_16x16x32_bf16(afh[mi], bfl[ni],
                                                                      acc[mi][ni], 0, 0, 0);
                acc[mi][ni] = __builtin_amdgcn_mfma_f32_16x16x32_bf16(afl[mi], bfh[ni],
                                                                      acc[mi][ni], 0, 0, 0);
            }
        __syncthreads();
    }
    // ---- epilogue: C/D layout col=l16, row=quad*4+reg; scale by ns, emit fp16
#pragma unroll
    for (int mi = 0; mi < TM; ++mi)
#pragma unroll
        for (int r = 0; r < 4; ++r) {
            int row = m0 + mi * 16 + quad * 4 + r;
            if (row < M) {
                float s = ns[row];
#pragma unroll
                for (int ni = 0; ni < TN; ++ni) {
                    C[(size_t)row * N + n0 + wcol + ni * 16 + l16] =
                        __float2half(acc[mi][ni][r] * s);
                }
            }
        }
}

// ---------------- gather-row add helper ----------------
template <int VEC>
__device__ inline void load_add(float* a, const __half* p) {
    if (VEC == 4) {
        uint2 r = *(const uint2*)p;
        __half2 h0 = *reinterpret_cast<__half2*>(&r.x);
        __half2 h1 = *reinterpret_cast<__half2*>(&r.y);
        float2 f0 = __half22float2(h0);
        float2 f1 = __half22float2(h1);
        a[0] += f0.x; a[1] += f0.y; a[2] += f1.x; a[3] += f1.y;
    } else if (VEC == 2) {
        uint_t r = *(const uint_t*)p;
        __half2 h0 = *reinterpret_cast<__half2*>(&r);
        float2 f0 = __half22float2(h0);
        a[0] += f0.x; a[1] += f0.y;
    } else {
        a[0] += __half2float(*p);
    }
}

// ---------------- CSR aggregation + fused epilogue ----------------
// res = act(nd[w] * sum_{e: dst==w} tmp[src[e]] + bias)
// OUT_MODE: 0 = fp32 only, 1 = hi/lo planes only, 2 = both
template <int VEC, int RELU, int OUT_MODE>
__global__ void agg_ep_k(const __half* __restrict__ tmp, float* __restrict__ outF,
                         ushort_t* __restrict__ outH, ushort_t* __restrict__ outL,
                         const int* __restrict__ row_start, const int* __restrict__ edge_src,
                         const float* __restrict__ nd, const float* __restrict__ bias,
                         int n_nodes, int dim) {
    int w = (blockIdx.x * blockDim.x + threadIdx.x) >> 6;
    int lane = threadIdx.x & 63;
    if (w >= n_nodes) return;
    int s = row_start[w], e = row_start[w + 1];
    int col = lane * VEC;
    float acc[4][VEC];
#pragma unroll
    for (int c = 0; c < 4; ++c)
#pragma unroll
        for (int j = 0; j < VEC; ++j) acc[c][j] = 0.f;
    int i = s;
    for (; i + 3 < e; i += 4) {
        int u0 = edge_src[i];
        int u1 = edge_src[i + 1];
        int u2 = edge_src[i + 2];
        int u3 = edge_src[i + 3];
        load_add<VEC>(acc[0], tmp + (size_t)u0 * dim + col);
        load_add<VEC>(acc[1], tmp + (size_t)u1 * dim + col);
        load_add<VEC>(acc[2], tmp + (size_t)u2 * dim + col);
        load_add<VEC>(acc[3], tmp + (size_t)u3 * dim + col);
    }
    for (; i < e; ++i) {
        int u = edge_src[i];
        load_add<VEC>(acc[0], tmp + (size_t)u * dim + col);
    }
    float d = nd[w];
    float r[VEC];
#pragma unroll
    for (int j = 0; j < VEC; ++j) {
        float v = fmaf((acc[0][j] + acc[1][j]) + (acc[2][j] + acc[3][j]), d, bias[col + j]);
        r[j] = RELU ? fmaxf(v, 0.f) : v;
    }
    size_t base = (size_t)w * dim + col;
    if (OUT_MODE != 1) {
        if (VEC == 4) {
            *(float4*)(outF + base) = make_float4(r[0], r[1], r[2], r[3]);
        } else if (VEC == 2) {
            *(float2*)(outF + base) = make_float2(r[0], r[1]);
        } else {
            outF[base] = r[0];
        }
    }
    if (OUT_MODE != 0) {
        ushort_t h[VEC], l[VEC];
#pragma unroll
        for (int j = 0; j < VEC; ++j) split1(r[j], h[j], l[j]);
        if (VEC == 4) {
            *(ushort4*)(outH + base) = make_ushort4(h[0], h[1], h[2], h[3]);
            *(ushort4*)(outL + base) = make_ushort4(l[0], l[1], l[2], l[3]);
        } else if (VEC == 2) {
            *(ushort2*)(outH + base) = make_ushort2(h[0], h[1]);
            *(ushort2*)(outL + base) = make_ushort2(l[0], l[1]);
        } else {
            outH[base] = h[0];
            outL[base] = l[0];
        }
    }
}

extern "C" void kernel_launch(void* const* d_in, const int* in_sizes, int n_in,
                              void* d_out, int out_size, void* d_ws, size_t ws_size,
                              hipStream_t stream) {
    const float* features = (const float*)d_in[0];
    const int* src = (const int*)d_in[1];
    const int* dst = (const int*)d_in[2];
    const float* W0 = (const float*)d_in[3];
    const float* b0 = (const float*)d_in[4];
    const float* W1 = (const float*)d_in[5];
    const float* b1 = (const float*)d_in[6];
    const float* W2 = (const float*)d_in[7];
    const float* b2 = (const float*)d_in[8];
    const float* W3 = (const float*)d_in[9];
    const float* b3 = (const float*)d_in[10];
    float* out = (float*)d_out;

    // workspace carve (~160 MB)
    char* p = (char*)d_ws;
    auto alloc = [&](size_t bytes) {
        void* r = (void*)p;
        p += (bytes + 255) & ~(size_t)255;
        return r;
    };
    __half* tmp = (__half*)alloc((size_t)N_NODES * 256 * 2);        // 25.6 MB GEMM out (fp16)
    ushort_t* H1hi = (ushort_t*)alloc((size_t)N_NODES * 256 * 2);   // [M][256]
    ushort_t* H1lo = (ushort_t*)alloc((size_t)N_NODES * 256 * 2);
    ushort_t* H2hi = (ushort_t*)alloc((size_t)N_NODES * 256 * 2);   // [M][256]
    ushort_t* H2lo = (ushort_t*)alloc((size_t)N_NODES * 256 * 2);
    ushort_t* H3hi = (ushort_t*)alloc((size_t)N_NODES * 128 * 2);   // [M][128]
    ushort_t* H3lo = (ushort_t*)alloc((size_t)N_NODES * 128 * 2);
    ushort_t* W0hi = (ushort_t*)alloc(512 * 256 * 2);               // Wt planes [N][K]
    ushort_t* W0lo = (ushort_t*)alloc(512 * 256 * 2);
    ushort_t* W1hi = (ushort_t*)alloc(256 * 256 * 2);
    ushort_t* W1lo = (ushort_t*)alloc(256 * 256 * 2);
    ushort_t* W2hi = (ushort_t*)alloc(256 * 128 * 2);
    ushort_t* W2lo = (ushort_t*)alloc(256 * 128 * 2);
    ushort_t* W3hi = (ushort_t*)alloc(128 * 64 * 2);
    ushort_t* W3lo = (ushort_t*)alloc(128 * 64 * 2);
    int* edge_src = (int*)alloc((size_t)N_EDGES * 4);
    int* row_start = (int*)alloc((size_t)(N_NODES + 1) * 4);
    int* cursor = (int*)alloc((size_t)N_NODES * 4);
    int* degO = (int*)alloc((size_t)N_NODES * 4);
    int* degI = (int*)alloc((size_t)N_NODES * 4);
    float* ns = (float*)alloc((size_t)N_NODES * 4);
    float* nd = (float*)alloc((size_t)N_NODES * 4);

    // ---- graph preprocessing ----
    hipMemsetAsync(degO, 0, (size_t)N_NODES * 4, stream);
    hipMemsetAsync(degI, 0, (size_t)N_NODES * 4, stream);
    count_deg_k<<<(N_EDGES + 255) / 256, 256, 0, stream>>>(src, dst, N_EDGES, degO, degI);
    norm_k<<<(N_NODES + 255) / 256, 256, 0, stream>>>(degO, degI, ns, nd, N_NODES);
    scan_k<<<1, 1024, 0, stream>>>(degI, row_start, cursor, N_NODES);
    fill_csr_k<<<(N_EDGES + 255) / 256, 256, 0, stream>>>(src, dst, N_EDGES, cursor, edge_src);

    // ---- weight splits (one launch) ----
    {
        const int tot = 512 * 256 + 256 * 256 + 256 * 128 + 128 * 64;
        split_weights_k<<<(tot + 255) / 256, 256, 0, stream>>>(
            W0, W1, W2, W3, W0hi, W0lo, W1hi, W1lo, W2hi, W2lo, W3hi, W3lo);
    }

    const int gm = (N_NODES + 63) / 64;       // 782 blocks, BM=64
    const int aggBlocks = (N_NODES + 3) / 4;  // 4 waves/block

    // ---- layer 0: 512 -> 256 (feature split fused into staging, done once/row) ----
    gemm_mfma_k<256, 1><<<dim3(gm, 1), 256, 0, stream>>>(features, nullptr, nullptr,
                                                         W0hi, W0lo, tmp, N_NODES, 512, 256, ns);
    agg_ep_k<4, 1, 1><<<aggBlocks, 256, 0, stream>>>(tmp, nullptr, H1hi, H1lo, row_start,
                                                     edge_src, nd, b0, N_NODES, 256);

    // ---- layer 1: 256 -> 256 ----
    gemm_mfma_k<256, 0><<<dim3(gm, 1), 256, 0, stream>>>(nullptr, H1hi, H1lo, W1hi, W1lo,
                                                         tmp, N_NODES, 256, 256, ns);
    agg_ep_k<4, 1, 1><<<aggBlocks, 256, 0, stream>>>(tmp, nullptr, H2hi, H2lo, row_start,
                                                     edge_src, nd, b1, N_NODES, 256);

    // ---- layer 2: 256 -> 128 (aspect_embed -> d_out, planes for L3) ----
    gemm_mfma_k<128, 0><<<dim3(gm, 1), 256, 0, stream>>>(nullptr, H2hi, H2lo, W2hi, W2lo,
                                                         tmp, N_NODES, 256, 128, ns);
    agg_ep_k<2, 0, 2><<<aggBlocks, 256, 0, stream>>>(tmp, out, H3hi, H3lo, row_start,
                                                     edge_src, nd, b2, N_NODES, 128);

    // ---- layer 3: 128 -> 64 (h -> d_out + 50000*128) ----
    gemm_mfma_k<64, 0><<<dim3(gm, 1), 256, 0, stream>>>(nullptr, H3hi, H3lo, W3hi, W3lo,
                                                        tmp, N_NODES, 128, 64, ns);
    agg_ep_k<1, 0, 0><<<aggBlocks, 256, 0, stream>>>(tmp, out + (size_t)N_NODES * 128,
                                                     nullptr, nullptr, row_start, edge_src,
                                                     nd, b3, N_NODES, 64);
}

// Round 3
// 621.494 us; speedup vs baseline: 1.0499x; 1.0499x over previous
//
#include <hip/hip_runtime.h>
#include <hip/hip_bf16.h>
#include <hip/hip_fp16.h>

#define N_NODES 50000
#define N_EDGES 800000

typedef unsigned short ushort_t;
typedef unsigned int uint_t;
typedef __attribute__((ext_vector_type(8))) short short8;
typedef __attribute__((ext_vector_type(4))) float f32x4;

// ---------------- bf16 split helpers ----------------
__device__ inline ushort_t bf16_rne(float x) {
    uint_t u = __float_as_uint(x);
    uint_t r = (u + 0x7fffu + ((u >> 16) & 1u)) >> 16;
    return (ushort_t)r;
}
__device__ inline void split1(float x, ushort_t& h, ushort_t& l) {
    ushort_t hh = bf16_rne(x);
    float fh = __uint_as_float((uint_t)hh << 16);
    h = hh;
    l = bf16_rne(x - fh);
}

// ---------------- async global->LDS (16B per lane, wave-uniform LDS base) ----
__device__ inline void gl_lds16(const void* g, void* l) {
    __builtin_amdgcn_global_load_lds(
        (const __attribute__((address_space(1))) unsigned int*)g,
        (__attribute__((address_space(3))) unsigned int*)l, 16, 0, 0);
}

// ---------------- degree count ----------------
__global__ void count_deg_k(const int* __restrict__ src, const int* __restrict__ dst,
                            int n_edges, int* __restrict__ deg_out, int* __restrict__ deg_in) {
    int i = blockIdx.x * blockDim.x + threadIdx.x;
    if (i < n_edges) {
        atomicAdd(&deg_out[src[i]], 1);
        atomicAdd(&deg_in[dst[i]], 1);
    }
}

// ---------------- norms ----------------
__global__ void norm_k(const int* __restrict__ deg_out, const int* __restrict__ deg_in,
                       float* __restrict__ ns, float* __restrict__ nd, int n) {
    int i = blockIdx.x * blockDim.x + threadIdx.x;
    if (i < n) {
        ns[i] = 1.0f / sqrtf((float)max(deg_out[i], 1));
        nd[i] = 1.0f / sqrtf((float)max(deg_in[i], 1));
    }
}

// ---------------- exclusive scan (single block, shfl-based) ----------------
__global__ void scan_k(const int* __restrict__ deg, int* __restrict__ row_start,
                       int* __restrict__ cursor, int n) {
    __shared__ int wexcl[16];
    __shared__ int chunk_total;
    __shared__ int carry_s;
    const int tid = threadIdx.x;
    const int lane = tid & 63, wid = tid >> 6;
    if (tid == 0) carry_s = 0;
    for (int base = 0; base < n; base += 1024) {
        int i = base + tid;
        int v = (i < n) ? deg[i] : 0;
        // inclusive wave scan
        int x = v;
#pragma unroll
        for (int off = 1; off < 64; off <<= 1) {
            int y = __shfl_up(x, off, 64);
            if (lane >= off) x += y;
        }
        __syncthreads();  // protect wexcl reuse across chunks; orders carry_s update
        if (lane == 63) wexcl[wid] = x;
        __syncthreads();
        if (wid == 0) {
            int tv = (lane < 16) ? wexcl[lane] : 0;
            int xs = tv;
#pragma unroll
            for (int off = 1; off < 16; off <<= 1) {
                int y = __shfl_up(xs, off, 64);
                if (lane >= off) xs += y;
            }
            if (lane < 16) wexcl[lane] = xs - tv;  // exclusive wave offset
            if (lane == 15) chunk_total = xs;
        }
        __syncthreads();
        int carry = carry_s;
        if (i < n) {
            int o = carry + wexcl[wid] + x - v;
            row_start[i] = o;
            cursor[i] = o;
        }
        __syncthreads();  // all reads of carry_s done
        if (tid == 0) carry_s = carry + chunk_total;
    }
    if (tid == 0) row_start[n] = carry_s;
}

// ---------------- CSR fill ----------------
__global__ void fill_csr_k(const int* __restrict__ src, const int* __restrict__ dst,
                           int n_edges, int* __restrict__ cursor, int* __restrict__ edge_src) {
    int i = blockIdx.x * blockDim.x + threadIdx.x;
    if (i < n_edges) {
        int pos = atomicAdd(&cursor[dst[i]], 1);
        edge_src[pos] = src[i];
    }
}

// ---------------- split+transpose all 4 weights in one launch ----------------
__global__ void split_weights_k(const float* __restrict__ W0, const float* __restrict__ W1,
                                const float* __restrict__ W2, const float* __restrict__ W3,
                                ushort_t* __restrict__ W0h, ushort_t* __restrict__ W0l,
                                ushort_t* __restrict__ W1h, ushort_t* __restrict__ W1l,
                                ushort_t* __restrict__ W2h, ushort_t* __restrict__ W2l,
                                ushort_t* __restrict__ W3h, ushort_t* __restrict__ W3l) {
    const int s0 = 512 * 256, s1 = s0 + 256 * 256, s2 = s1 + 256 * 128, s3 = s2 + 128 * 64;
    int idx = blockIdx.x * blockDim.x + threadIdx.x;
    const float* W;
    ushort_t *H, *L;
    int K, N, local;
    if (idx < s0) { W = W0; H = W0h; L = W0l; K = 512; N = 256; local = idx; }
    else if (idx < s1) { W = W1; H = W1h; L = W1l; K = 256; N = 256; local = idx - s0; }
    else if (idx < s2) { W = W2; H = W2h; L = W2l; K = 256; N = 128; local = idx - s1; }
    else if (idx < s3) { W = W3; H = W3h; L = W3l; K = 128; N = 64; local = idx - s2; }
    else return;
    int n = local / K;
    int k = local - n * K;
    split1(W[(size_t)k * N + n], H[local], L[local]);
}

// ---------------- MFMA GEMM: C[M,N] = fp16( ns[row] * (A @ W) ), bf16x2 3-pass ----
// Round-1 geometry: BM=128, BN=128/64, grid.y = N/BN.
// ASRC=0: A as hi/lo bf16 planes [M][K], staged via global_load_lds (async DMA).
// ASRC=1: A fp32 [M][K], split inline; fp32 loads SOFTWARE-PIPELINED one K-step
//         ahead (issued after the first barrier, consumed at next iteration's
//         split) so HBM latency hides under the MFMA phase.
// W as transposed hi/lo planes [N][K], staged via global_load_lds.
// LDS layout linear in chunk order: chunk c (row c>>2, k-octet c&3) at bytes [16c,16c+16).
template <int BN, int ASRC>  // BN: 128 or 64
__global__ __launch_bounds__(256) void gemm_mfma_k(
    const float* __restrict__ Af,
    const ushort_t* __restrict__ Ahi, const ushort_t* __restrict__ Alo,
    const ushort_t* __restrict__ Bhi, const ushort_t* __restrict__ Blo,
    __half* __restrict__ C, int M, int K, int N, const float* __restrict__ ns) {
    constexpr int BM = 128, BK = 32;
    constexpr int WN = (BN == 128) ? 2 : 1;
    constexpr int TM = BM / ((4 / WN) * 16);
    constexpr int TN = BN / (WN * 16);
    __shared__ __attribute__((aligned(16))) ushort_t Ah[BM * BK];
    __shared__ __attribute__((aligned(16))) ushort_t Al[BM * BK];
    __shared__ __attribute__((aligned(16))) ushort_t Bh[BN * BK];
    __shared__ __attribute__((aligned(16))) ushort_t Bl[BN * BK];
    const int t = threadIdx.x;
    const int wave = t >> 6, lane = t & 63;
    const int quad = lane >> 4, l16 = lane & 15;
    const int m0 = blockIdx.x * BM, n0 = blockIdx.y * BN;
    const int wrow = (wave / WN) * (TM * 16);
    const int wcol = (wave % WN) * (TN * 16);

    f32x4 acc[TM][TN];
#pragma unroll
    for (int mi = 0; mi < TM; ++mi)
#pragma unroll
        for (int ni = 0; ni < TN; ++ni) acc[mi][ni] = (f32x4){0.f, 0.f, 0.f, 0.f};

    // prefetch regs for ASRC=1 (statically indexed; live across MFMA phase)
    float4 pv[2][2];
    auto loadA = [&](int kq) {
#pragma unroll
        for (int j = 0; j < 2; ++j) {
            int c = t + j * 256;
            int r = c >> 2, q = c & 3;
            int gr = m0 + r;
            if (gr >= M) gr = M - 1;
            const float* ap = Af + (size_t)gr * K + kq + q * 8;
            pv[j][0] = *(const float4*)ap;
            pv[j][1] = *(const float4*)(ap + 4);
        }
    };
    if (ASRC == 1) loadA(0);

    for (int k0 = 0; k0 < K; k0 += BK) {
        // ---- stage B first (async DMA flies during A split / A DMA)
#pragma unroll
        for (int j = 0; j < BN / 64; ++j) {
            int cg = wave * (BN / 64) + j;
            int c = cg * 64 + lane;
            int r = c >> 2, q = c & 3;
            size_t goff = (size_t)(n0 + r) * K + k0 + q * 8;
            gl_lds16(Bhi + goff, &Bh[cg * 512]);
            gl_lds16(Blo + goff, &Bl[cg * 512]);
        }
        // ---- stage A
        if (ASRC == 0) {
#pragma unroll
            for (int j = 0; j < 2; ++j) {
                int cg = wave * 2 + j;     // 0..7
                int c = cg * 64 + lane;    // chunk 0..511
                int r = c >> 2, q = c & 3;
                int gr = m0 + r;
                if (gr >= M) gr = M - 1;
                size_t goff = (size_t)gr * K + k0 + q * 8;
                gl_lds16(Ahi + goff, &Ah[cg * 512]);
                gl_lds16(Alo + goff, &Al[cg * 512]);
            }
        } else {
            // split prefetched fp32 -> bf16 hi/lo, write LDS
#pragma unroll
            for (int j = 0; j < 2; ++j) {
                int c = t + j * 256;
                float vv[8] = {pv[j][0].x, pv[j][0].y, pv[j][0].z, pv[j][0].w,
                               pv[j][1].x, pv[j][1].y, pv[j][1].z, pv[j][1].w};
                short8 hh, ll;
#pragma unroll
                for (int ee = 0; ee < 8; ++ee) {
                    ushort_t h, l;
                    split1(vv[ee], h, l);
                    hh[ee] = (short)h;
                    ll[ee] = (short)l;
                }
                *(short8*)&Ah[c * 8] = hh;
                *(short8*)&Al[c * 8] = ll;
            }
        }
        __syncthreads();
        // ---- issue next K-step's A loads; latency hides under MFMA phase
        if (ASRC == 1 && k0 + BK < K) loadA(k0 + BK);
        // ---- fragments: A[m=l16][k=quad*8+j], B[k=quad*8+j][n=l16]
        short8 afh[TM], afl[TM], bfh[TN], bfl[TN];
#pragma unroll
        for (int mi = 0; mi < TM; ++mi) {
            int m = wrow + mi * 16 + l16;
            afh[mi] = *(const short8*)&Ah[m * BK + quad * 8];
            afl[mi] = *(const short8*)&Al[m * BK + quad * 8];
        }
#pragma unroll
        for (int ni = 0; ni < TN; ++ni) {
            int n = wcol + ni * 16 + l16;
            bfh[ni] = *(const short8*)&Bh[n * BK + quad * 8];
            bfl[ni] = *(const short8*)&Bl[n * BK + quad * 8];
        }
#pragma unroll
        for (int mi = 0; mi < TM; ++mi)
#pragma unroll
            for (int ni = 0; ni < TN; ++ni) {
                acc[mi][ni] = __builtin_amdgcn_mfma_f32_16x16x32_bf16(afh[mi], bfh[ni],
                                                                      acc[mi][ni], 0, 0, 0);
                acc[mi][ni] = __builtin_amdgcn_mfma_f32_16x16x32_bf16(afh[mi], bfl[ni],
                                                                      acc[mi][ni], 0, 0, 0);
                acc[mi][ni] = __builtin_amdgcn_mfma_f32_16x16x32_bf16(afl[mi], bfh[ni],
                                                                      acc[mi][ni], 0, 0, 0);
            }
        __syncthreads();
    }
    // ---- epilogue: C/D layout col=l16, row=quad*4+reg; scale by ns, emit fp16
#pragma unroll
    for (int mi = 0; mi < TM; ++mi)
#pragma unroll
        for (int r = 0; r < 4; ++r) {
            int row = m0 + wrow + mi * 16 + quad * 4 + r;
            if (row < M) {
                float s = ns[row];
#pragma unroll
                for (int ni = 0; ni < TN; ++ni) {
                    C[(size_t)row * N + n0 + wcol + ni * 16 + l16] =
                        __float2half(acc[mi][ni][r] * s);
                }
            }
        }
}

// ---------------- gather-row raw load/accumulate helpers ----------------
template <int VEC> struct RawT { using T = uint2; };
template <> struct RawT<2> { using T = uint_t; };
template <> struct RawT<1> { using T = ushort_t; };

template <int VEC>
__device__ inline typename RawT<VEC>::T load_raw(const __half* p) {
    return *(const typename RawT<VEC>::T*)p;
}
template <int VEC>
__device__ inline void add_raw(float* a, typename RawT<VEC>::T r) {
    if (VEC == 4) {
        uint2 v = *(uint2*)&r;
        __half2 h0 = *reinterpret_cast<__half2*>(&v.x);
        __half2 h1 = *reinterpret_cast<__half2*>(&v.y);
        float2 f0 = __half22float2(h0);
        float2 f1 = __half22float2(h1);
        a[0] += f0.x; a[1] += f0.y; a[2] += f1.x; a[3] += f1.y;
    } else if (VEC == 2) {
        uint_t v = *(uint_t*)&r;
        __half2 h0 = *reinterpret_cast<__half2*>(&v);
        float2 f0 = __half22float2(h0);
        a[0] += f0.x; a[1] += f0.y;
    } else {
        ushort_t v = *(ushort_t*)&r;
        a[0] += __half2float(*reinterpret_cast<__half*>(&v));
    }
}
template <int VEC>
__device__ inline void load_add(float* a, const __half* p) {
    add_raw<VEC>(a, load_raw<VEC>(p));
}

// ---------------- CSR aggregation + fused epilogue ----------------
// res = act(nd[w] * sum_{e: dst==w} tmp[src[e]] + bias)
// OUT_MODE: 0 = fp32 only, 1 = hi/lo planes only, 2 = both
// 8-deep gather batching: 8 outstanding row loads per wave before any add.
// Accumulation order into acc[j&3] is identical to the old 4-wide loop.
template <int VEC, int RELU, int OUT_MODE>
__global__ void agg_ep_k(const __half* __restrict__ tmp, float* __restrict__ outF,
                         ushort_t* __restrict__ outH, ushort_t* __restrict__ outL,
                         const int* __restrict__ row_start, const int* __restrict__ edge_src,
                         const float* __restrict__ nd, const float* __restrict__ bias,
                         int n_nodes, int dim) {
    int w = (blockIdx.x * blockDim.x + threadIdx.x) >> 6;
    int lane = threadIdx.x & 63;
    if (w >= n_nodes) return;
    int s = row_start[w], e = row_start[w + 1];
    int col = lane * VEC;
    float acc[4][VEC];
#pragma unroll
    for (int c = 0; c < 4; ++c)
#pragma unroll
        for (int j = 0; j < VEC; ++j) acc[c][j] = 0.f;
    int i = s;
    for (; i + 7 < e; i += 8) {
        int u[8];
#pragma unroll
        for (int j = 0; j < 8; ++j) u[j] = edge_src[i + j];
        typename RawT<VEC>::T r[8];
#pragma unroll
        for (int j = 0; j < 8; ++j) r[j] = load_raw<VEC>(tmp + (size_t)u[j] * dim + col);
#pragma unroll
        for (int j = 0; j < 8; ++j) add_raw<VEC>(acc[j & 3], r[j]);
    }
    for (; i + 3 < e; i += 4) {
        int u0 = edge_src[i];
        int u1 = edge_src[i + 1];
        int u2 = edge_src[i + 2];
        int u3 = edge_src[i + 3];
        load_add<VEC>(acc[0], tmp + (size_t)u0 * dim + col);
        load_add<VEC>(acc[1], tmp + (size_t)u1 * dim + col);
        load_add<VEC>(acc[2], tmp + (size_t)u2 * dim + col);
        load_add<VEC>(acc[3], tmp + (size_t)u3 * dim + col);
    }
    for (; i < e; ++i) {
        int u = edge_src[i];
        load_add<VEC>(acc[0], tmp + (size_t)u * dim + col);
    }
    float d = nd[w];
    float r[VEC];
#pragma unroll
    for (int j = 0; j < VEC; ++j) {
        float v = fmaf((acc[0][j] + acc[1][j]) + (acc[2][j] + acc[3][j]), d, bias[col + j]);
        r[j] = RELU ? fmaxf(v, 0.f) : v;
    }
    size_t base = (size_t)w * dim + col;
    if (OUT_MODE != 1) {
        if (VEC == 4) {
            *(float4*)(outF + base) = make_float4(r[0], r[1], r[2], r[3]);
        } else if (VEC == 2) {
            *(float2*)(outF + base) = make_float2(r[0], r[1]);
        } else {
            outF[base] = r[0];
        }
    }
    if (OUT_MODE != 0) {
        ushort_t h[VEC], l[VEC];
#pragma unroll
        for (int j = 0; j < VEC; ++j) split1(r[j], h[j], l[j]);
        if (VEC == 4) {
            *(ushort4*)(outH + base) = make_ushort4(h[0], h[1], h[2], h[3]);
            *(ushort4*)(outL + base) = make_ushort4(l[0], l[1], l[2], l[3]);
        } else if (VEC == 2) {
            *(ushort2*)(outH + base) = make_ushort2(h[0], h[1]);
            *(ushort2*)(outL + base) = make_ushort2(l[0], l[1]);
        } else {
            outH[base] = h[0];
            outL[base] = l[0];
        }
    }
}

extern "C" void kernel_launch(void* const* d_in, const int* in_sizes, int n_in,
                              void* d_out, int out_size, void* d_ws, size_t ws_size,
                              hipStream_t stream) {
    const float* features = (const float*)d_in[0];
    const int* src = (const int*)d_in[1];
    const int* dst = (const int*)d_in[2];
    const float* W0 = (const float*)d_in[3];
    const float* b0 = (const float*)d_in[4];
    const float* W1 = (const float*)d_in[5];
    const float* b1 = (const float*)d_in[6];
    const float* W2 = (const float*)d_in[7];
    const float* b2 = (const float*)d_in[8];
    const float* W3 = (const float*)d_in[9];
    const float* b3 = (const float*)d_in[10];
    float* out = (float*)d_out;

    // workspace carve (~160 MB)
    char* p = (char*)d_ws;
    auto alloc = [&](size_t bytes) {
        void* r = (void*)p;
        p += (bytes + 255) & ~(size_t)255;
        return r;
    };
    __half* tmp = (__half*)alloc((size_t)N_NODES * 256 * 2);        // 25.6 MB GEMM out (fp16)
    ushort_t* H1hi = (ushort_t*)alloc((size_t)N_NODES * 256 * 2);   // [M][256]
    ushort_t* H1lo = (ushort_t*)alloc((size_t)N_NODES * 256 * 2);
    ushort_t* H2hi = (ushort_t*)alloc((size_t)N_NODES * 256 * 2);   // [M][256]
    ushort_t* H2lo = (ushort_t*)alloc((size_t)N_NODES * 256 * 2);
    ushort_t* H3hi = (ushort_t*)alloc((size_t)N_NODES * 128 * 2);   // [M][128]
    ushort_t* H3lo = (ushort_t*)alloc((size_t)N_NODES * 128 * 2);
    ushort_t* W0hi = (ushort_t*)alloc(512 * 256 * 2);               // Wt planes [N][K]
    ushort_t* W0lo = (ushort_t*)alloc(512 * 256 * 2);
    ushort_t* W1hi = (ushort_t*)alloc(256 * 256 * 2);
    ushort_t* W1lo = (ushort_t*)alloc(256 * 256 * 2);
    ushort_t* W2hi = (ushort_t*)alloc(256 * 128 * 2);
    ushort_t* W2lo = (ushort_t*)alloc(256 * 128 * 2);
    ushort_t* W3hi = (ushort_t*)alloc(128 * 64 * 2);
    ushort_t* W3lo = (ushort_t*)alloc(128 * 64 * 2);
    int* edge_src = (int*)alloc((size_t)N_EDGES * 4);
    int* row_start = (int*)alloc((size_t)(N_NODES + 1) * 4);
    int* cursor = (int*)alloc((size_t)N_NODES * 4);
    int* degO = (int*)alloc((size_t)N_NODES * 4);
    int* degI = (int*)alloc((size_t)N_NODES * 4);
    float* ns = (float*)alloc((size_t)N_NODES * 4);
    float* nd = (float*)alloc((size_t)N_NODES * 4);

    // ---- graph preprocessing ----
    hipMemsetAsync(degO, 0, (size_t)N_NODES * 4, stream);
    hipMemsetAsync(degI, 0, (size_t)N_NODES * 4, stream);
    count_deg_k<<<(N_EDGES + 255) / 256, 256, 0, stream>>>(src, dst, N_EDGES, degO, degI);
    norm_k<<<(N_NODES + 255) / 256, 256, 0, stream>>>(degO, degI, ns, nd, N_NODES);
    scan_k<<<1, 1024, 0, stream>>>(degI, row_start, cursor, N_NODES);
    fill_csr_k<<<(N_EDGES + 255) / 256, 256, 0, stream>>>(src, dst, N_EDGES, cursor, edge_src);

    // ---- weight splits (one launch) ----
    {
        const int tot = 512 * 256 + 256 * 256 + 256 * 128 + 128 * 64;
        split_weights_k<<<(tot + 255) / 256, 256, 0, stream>>>(
            W0, W1, W2, W3, W0hi, W0lo, W1hi, W1lo, W2hi, W2lo, W3hi, W3lo);
    }

    const int gm = (N_NODES + 127) / 128;     // 391 blocks, BM=128
    const int aggBlocks = (N_NODES + 3) / 4;  // 4 waves/block

    // ---- layer 0: 512 -> 256 (feature split fused into staging, A-prefetch) ----
    gemm_mfma_k<128, 1><<<dim3(gm, 2), 256, 0, stream>>>(features, nullptr, nullptr,
                                                         W0hi, W0lo, tmp, N_NODES, 512, 256, ns);
    agg_ep_k<4, 1, 1><<<aggBlocks, 256, 0, stream>>>(tmp, nullptr, H1hi, H1lo, row_start,
                                                     edge_src, nd, b0, N_NODES, 256);

    // ---- layer 1: 256 -> 256 ----
    gemm_mfma_k<128, 0><<<dim3(gm, 2), 256, 0, stream>>>(nullptr, H1hi, H1lo, W1hi, W1lo,
                                                         tmp, N_NODES, 256, 256, ns);
    agg_ep_k<4, 1, 1><<<aggBlocks, 256, 0, stream>>>(tmp, nullptr, H2hi, H2lo, row_start,
                                                     edge_src, nd, b1, N_NODES, 256);

    // ---- layer 2: 256 -> 128 (aspect_embed -> d_out, planes for L3) ----
    gemm_mfma_k<128, 0><<<dim3(gm, 1), 256, 0, stream>>>(nullptr, H2hi, H2lo, W2hi, W2lo,
                                                         tmp, N_NODES, 256, 128, ns);
    agg_ep_k<2, 0, 2><<<aggBlocks, 256, 0, stream>>>(tmp, out, H3hi, H3lo, row_start,
                                                     edge_src, nd, b2, N_NODES, 128);

    // ---- layer 3: 128 -> 64 (h -> d_out + 50000*128) ----
    gemm_mfma_k<64, 0><<<dim3(gm, 1), 256, 0, stream>>>(nullptr, H3hi, H3lo, W3hi, W3lo,
                                                        tmp, N_NODES, 128, 64, ns);
    agg_ep_k<1, 0, 0><<<aggBlocks, 256, 0, stream>>>(tmp, out + (size_t)N_NODES * 128,
                                                     nullptr, nullptr, row_start, edge_src,
                                                     nd, b3, N_NODES, 64);
}

// Round 4
// 587.538 us; speedup vs baseline: 1.1106x; 1.0578x over previous
//
#include <hip/hip_runtime.h>
#include <hip/hip_bf16.h>
#include <hip/hip_fp16.h>

#define N_NODES 50000
#define N_EDGES 800000

typedef unsigned short ushort_t;
typedef unsigned int uint_t;
typedef __attribute__((ext_vector_type(8))) short short8;
typedef __attribute__((ext_vector_type(4))) float f32x4;

// ---------------- bf16 split helpers ----------------
__device__ inline ushort_t bf16_rne(float x) {
    uint_t u = __float_as_uint(x);
    uint_t r = (u + 0x7fffu + ((u >> 16) & 1u)) >> 16;
    return (ushort_t)r;
}
__device__ inline void split1(float x, ushort_t& h, ushort_t& l) {
    ushort_t hh = bf16_rne(x);
    float fh = __uint_as_float((uint_t)hh << 16);
    h = hh;
    l = bf16_rne(x - fh);
}

// ---------------- async global->LDS (16B per lane, wave-uniform LDS base) ----
__device__ inline void gl_lds16(const void* g, void* l) {
    __builtin_amdgcn_global_load_lds(
        (const __attribute__((address_space(1))) unsigned int*)g,
        (__attribute__((address_space(3))) unsigned int*)l, 16, 0, 0);
}

// ---------------- degree count ----------------
__global__ void count_deg_k(const int* __restrict__ src, const int* __restrict__ dst,
                            int n_edges, int* __restrict__ deg_out, int* __restrict__ deg_in) {
    int i = blockIdx.x * blockDim.x + threadIdx.x;
    if (i < n_edges) {
        atomicAdd(&deg_out[src[i]], 1);
        atomicAdd(&deg_in[dst[i]], 1);
    }
}

// ---------------- norms ----------------
__global__ void norm_k(const int* __restrict__ deg_out, const int* __restrict__ deg_in,
                       float* __restrict__ ns, float* __restrict__ nd, int n) {
    int i = blockIdx.x * blockDim.x + threadIdx.x;
    if (i < n) {
        ns[i] = 1.0f / sqrtf((float)max(deg_out[i], 1));
        nd[i] = 1.0f / sqrtf((float)max(deg_in[i], 1));
    }
}

// ---------------- parallel exclusive scan (3 kernels) ----------------
// pass 1: per-block (1024-wide) local exclusive scan + block totals
__global__ void scan_local_k(const int* __restrict__ deg, int* __restrict__ row_start,
                             int* __restrict__ bsum, int n) {
    __shared__ int wexcl[16];
    const int tid = threadIdx.x;
    const int lane = tid & 63, wid = tid >> 6;
    const int i = blockIdx.x * 1024 + tid;
    int v = (i < n) ? deg[i] : 0;
    int x = v;
#pragma unroll
    for (int off = 1; off < 64; off <<= 1) {
        int y = __shfl_up(x, off, 64);
        if (lane >= off) x += y;
    }
    if (lane == 63) wexcl[wid] = x;
    __syncthreads();
    if (wid == 0) {
        int tv = (lane < 16) ? wexcl[lane] : 0;
        int xs = tv;
#pragma unroll
        for (int off = 1; off < 16; off <<= 1) {
            int y = __shfl_up(xs, off, 64);
            if (lane >= off) xs += y;
        }
        if (lane < 16) wexcl[lane] = xs - tv;
    }
    __syncthreads();
    int excl = wexcl[wid] + x - v;
    if (i < n) row_start[i] = excl;
    if (tid == 1023) bsum[blockIdx.x] = excl + v;  // block total (pad lanes have v=0)
}
// pass 2: single wave scans block totals (nb <= 64), writes grand total
__global__ void scan_bsum_k(int* __restrict__ bsum, int* __restrict__ total, int nb) {
    int lane = threadIdx.x;
    int v = (lane < nb) ? bsum[lane] : 0;
    int x = v;
#pragma unroll
    for (int off = 1; off < 64; off <<= 1) {
        int y = __shfl_up(x, off, 64);
        if (lane >= off) x += y;
    }
    if (lane < nb) bsum[lane] = x - v;  // exclusive
    if (lane == 63) *total = x;         // grand total
}
// pass 3: add block offsets, emit cursor copy
__global__ void scan_add_k(int* __restrict__ row_start, int* __restrict__ cursor,
                           const int* __restrict__ bsum, int n) {
    int i = blockIdx.x * blockDim.x + threadIdx.x;
    if (i < n) {
        int o = row_start[i] + bsum[i >> 10];
        row_start[i] = o;
        cursor[i] = o;
    }
}

// ---------------- CSR fill ----------------
__global__ void fill_csr_k(const int* __restrict__ src, const int* __restrict__ dst,
                           int n_edges, int* __restrict__ cursor, int* __restrict__ edge_src) {
    int i = blockIdx.x * blockDim.x + threadIdx.x;
    if (i < n_edges) {
        int pos = atomicAdd(&cursor[dst[i]], 1);
        edge_src[pos] = src[i];
    }
}

// ---------------- split+transpose all 4 weights in one launch ----------------
__global__ void split_weights_k(const float* __restrict__ W0, const float* __restrict__ W1,
                                const float* __restrict__ W2, const float* __restrict__ W3,
                                ushort_t* __restrict__ W0h, ushort_t* __restrict__ W0l,
                                ushort_t* __restrict__ W1h, ushort_t* __restrict__ W1l,
                                ushort_t* __restrict__ W2h, ushort_t* __restrict__ W2l,
                                ushort_t* __restrict__ W3h, ushort_t* __restrict__ W3l) {
    const int s0 = 512 * 256, s1 = s0 + 256 * 256, s2 = s1 + 256 * 128, s3 = s2 + 128 * 64;
    int idx = blockIdx.x * blockDim.x + threadIdx.x;
    const float* W;
    ushort_t *H, *L;
    int K, N, local;
    if (idx < s0) { W = W0; H = W0h; L = W0l; K = 512; N = 256; local = idx; }
    else if (idx < s1) { W = W1; H = W1h; L = W1l; K = 256; N = 256; local = idx - s0; }
    else if (idx < s2) { W = W2; H = W2h; L = W2l; K = 256; N = 128; local = idx - s1; }
    else if (idx < s3) { W = W3; H = W3h; L = W3l; K = 128; N = 64; local = idx - s2; }
    else return;
    int n = local / K;
    int k = local - n * K;
    split1(W[(size_t)k * N + n], H[local], L[local]);
}

// ---------------- MFMA GEMM: C[M,N] = fp16( ns[row] * (A @ W) ), bf16x2 3-pass ----
// Pipelined 2-phase (T3-min): double-buffered LDS; stage tile t+1 BEFORE
// computing tile t; ONE barrier per K-step. The implicit vmcnt(0) at the
// barrier waits for DMAs that had the whole MFMA phase to fly.
// ASRC=0: A as hi/lo bf16 planes [M][K], staged via global_load_lds (async DMA).
// ASRC=1: A fp32 [M][K]; fp32 loads pipelined one further step ahead in regs,
//         split into the NEXT LDS buffer during the current compute phase.
// W as transposed hi/lo planes [N][K], staged via global_load_lds.
// LDS layout linear in chunk order: chunk c (row c>>2, k-octet c&3) at bytes [16c,16c+16).
template <int BN, int ASRC>  // BN: 128 or 64
__global__ __launch_bounds__(256) void gemm_mfma_k(
    const float* __restrict__ Af,
    const ushort_t* __restrict__ Ahi, const ushort_t* __restrict__ Alo,
    const ushort_t* __restrict__ Bhi, const ushort_t* __restrict__ Blo,
    __half* __restrict__ C, int M, int K, int N, const float* __restrict__ ns) {
    constexpr int BM = 128, BK = 32;
    constexpr int WN = (BN == 128) ? 2 : 1;
    constexpr int TM = BM / ((4 / WN) * 16);
    constexpr int TN = BN / (WN * 16);
    __shared__ __attribute__((aligned(16))) ushort_t Ah[2][BM * BK];
    __shared__ __attribute__((aligned(16))) ushort_t Al[2][BM * BK];
    __shared__ __attribute__((aligned(16))) ushort_t Bh[2][BN * BK];
    __shared__ __attribute__((aligned(16))) ushort_t Bl[2][BN * BK];
    const int t = threadIdx.x;
    const int wave = t >> 6, lane = t & 63;
    const int quad = lane >> 4, l16 = lane & 15;
    const int m0 = blockIdx.x * BM, n0 = blockIdx.y * BN;
    const int wrow = (wave / WN) * (TM * 16);
    const int wcol = (wave % WN) * (TN * 16);

    f32x4 acc[TM][TN];
#pragma unroll
    for (int mi = 0; mi < TM; ++mi)
#pragma unroll
        for (int ni = 0; ni < TN; ++ni) acc[mi][ni] = (f32x4){0.f, 0.f, 0.f, 0.f};

    auto stageB = [&](int k0, int buf) {
#pragma unroll
        for (int j = 0; j < BN / 64; ++j) {
            int cg = wave * (BN / 64) + j;
            int c = cg * 64 + lane;
            int r = c >> 2, q = c & 3;
            size_t goff = (size_t)(n0 + r) * K + k0 + q * 8;
            gl_lds16(Bhi + goff, &Bh[buf][cg * 512]);
            gl_lds16(Blo + goff, &Bl[buf][cg * 512]);
        }
    };
    auto stageA_dma = [&](int k0, int buf) {
#pragma unroll
        for (int j = 0; j < 2; ++j) {
            int cg = wave * 2 + j;     // 0..7
            int c = cg * 64 + lane;    // chunk 0..511
            int r = c >> 2, q = c & 3;
            int gr = m0 + r;
            if (gr >= M) gr = M - 1;
            size_t goff = (size_t)gr * K + k0 + q * 8;
            gl_lds16(Ahi + goff, &Ah[buf][cg * 512]);
            gl_lds16(Alo + goff, &Al[buf][cg * 512]);
        }
    };
    // ASRC=1 register prefetch (statically indexed)
    float4 pv[2][2];
    auto loadA = [&](int kq) {
#pragma unroll
        for (int j = 0; j < 2; ++j) {
            int c = t + j * 256;
            int r = c >> 2, q = c & 3;
            int gr = m0 + r;
            if (gr >= M) gr = M - 1;
            const float* ap = Af + (size_t)gr * K + kq + q * 8;
            pv[j][0] = *(const float4*)ap;
            pv[j][1] = *(const float4*)(ap + 4);
        }
    };
    auto splitA = [&](int buf) {
#pragma unroll
        for (int j = 0; j < 2; ++j) {
            int c = t + j * 256;
            float vv[8] = {pv[j][0].x, pv[j][0].y, pv[j][0].z, pv[j][0].w,
                           pv[j][1].x, pv[j][1].y, pv[j][1].z, pv[j][1].w};
            short8 hh, ll;
#pragma unroll
            for (int ee = 0; ee < 8; ++ee) {
                ushort_t h, l;
                split1(vv[ee], h, l);
                hh[ee] = (short)h;
                ll[ee] = (short)l;
            }
            *(short8*)&Ah[buf][c * 8] = hh;
            *(short8*)&Al[buf][c * 8] = ll;
        }
    };

    // ---- prologue: fill buffer 0 with K-step 0
    stageB(0, 0);
    if (ASRC == 0) {
        stageA_dma(0, 0);
    } else {
        loadA(0);
        splitA(0);
        if (BK < K) loadA(BK);  // pv now holds step-1 data
    }
    __syncthreads();  // drains DMA (vmcnt) + LDS writes (lgkmcnt)

    int cur = 0;
    for (int k0 = 0; k0 < K; k0 += BK) {
        const int nxt = cur ^ 1;
        // ---- stage K-step t+1 into the other buffer; flies during compute
        if (k0 + BK < K) {
            stageB(k0 + BK, nxt);
            if (ASRC == 0) {
                stageA_dma(k0 + BK, nxt);
            } else {
                splitA(nxt);                       // consume pv (step t+1)
                if (k0 + 2 * BK < K) loadA(k0 + 2 * BK);  // refill pv (step t+2)
            }
        }
        // ---- fragments from buffer cur: A[m=l16][k=quad*8+j], B[k=quad*8+j][n=l16]
        short8 afh[TM], afl[TM], bfh[TN], bfl[TN];
#pragma unroll
        for (int mi = 0; mi < TM; ++mi) {
            int m = wrow + mi * 16 + l16;
            afh[mi] = *(const short8*)&Ah[cur][m * BK + quad * 8];
            afl[mi] = *(const short8*)&Al[cur][m * BK + quad * 8];
        }
#pragma unroll
        for (int ni = 0; ni < TN; ++ni) {
            int n = wcol + ni * 16 + l16;
            bfh[ni] = *(const short8*)&Bh[cur][n * BK + quad * 8];
            bfl[ni] = *(const short8*)&Bl[cur][n * BK + quad * 8];
        }
#pragma unroll
        for (int mi = 0; mi < TM; ++mi)
#pragma unroll
            for (int ni = 0; ni < TN; ++ni) {
                acc[mi][ni] = __builtin_amdgcn_mfma_f32_16x16x32_bf16(afh[mi], bfh[ni],
                                                                      acc[mi][ni], 0, 0, 0);
                acc[mi][ni] = __builtin_amdgcn_mfma_f32_16x16x32_bf16(afh[mi], bfl[ni],
                                                                      acc[mi][ni], 0, 0, 0);
                acc[mi][ni] = __builtin_amdgcn_mfma_f32_16x16x32_bf16(afl[mi], bfh[ni],
                                                                      acc[mi][ni], 0, 0, 0);
            }
        // ---- single barrier per K-step: all reads of cur done; nxt's DMA landed
        __syncthreads();
        cur = nxt;
    }
    // ---- epilogue: C/D layout col=l16, row=quad*4+reg; scale by ns, emit fp16
#pragma unroll
    for (int mi = 0; mi < TM; ++mi)
#pragma unroll
        for (int r = 0; r < 4; ++r) {
            int row = m0 + wrow + mi * 16 + quad * 4 + r;
            if (row < M) {
                float s = ns[row];
#pragma unroll
                for (int ni = 0; ni < TN; ++ni) {
                    C[(size_t)row * N + n0 + wcol + ni * 16 + l16] =
                        __float2half(acc[mi][ni][r] * s);
                }
            }
        }
}

// ---------------- gather-row raw load/accumulate helpers ----------------
template <int VEC> struct RawT { using T = uint2; };
template <> struct RawT<2> { using T = uint_t; };
template <> struct RawT<1> { using T = ushort_t; };

template <int VEC>
__device__ inline typename RawT<VEC>::T load_raw(const __half* p) {
    return *(const typename RawT<VEC>::T*)p;
}
template <int VEC>
__device__ inline void add_raw(float* a, typename RawT<VEC>::T r) {
    if (VEC == 4) {
        uint2 v = *(uint2*)&r;
        __half2 h0 = *reinterpret_cast<__half2*>(&v.x);
        __half2 h1 = *reinterpret_cast<__half2*>(&v.y);
        float2 f0 = __half22float2(h0);
        float2 f1 = __half22float2(h1);
        a[0] += f0.x; a[1] += f0.y; a[2] += f1.x; a[3] += f1.y;
    } else if (VEC == 2) {
        uint_t v = *(uint_t*)&r;
        __half2 h0 = *reinterpret_cast<__half2*>(&v);
        float2 f0 = __half22float2(h0);
        a[0] += f0.x; a[1] += f0.y;
    } else {
        ushort_t v = *(ushort_t*)&r;
        a[0] += __half2float(*reinterpret_cast<__half*>(&v));
    }
}
template <int VEC>
__device__ inline void load_add(float* a, const __half* p) {
    add_raw<VEC>(a, load_raw<VEC>(p));
}

// ---------------- CSR aggregation + fused epilogue ----------------
// res = act(nd[w] * sum_{e: dst==w} tmp[src[e]] + bias)
// OUT_MODE: 0 = fp32 only, 1 = hi/lo planes only, 2 = both
template <int VEC, int RELU, int OUT_MODE>
__global__ void agg_ep_k(const __half* __restrict__ tmp, float* __restrict__ outF,
                         ushort_t* __restrict__ outH, ushort_t* __restrict__ outL,
                         const int* __restrict__ row_start, const int* __restrict__ edge_src,
                         const float* __restrict__ nd, const float* __restrict__ bias,
                         int n_nodes, int dim) {
    int w = (blockIdx.x * blockDim.x + threadIdx.x) >> 6;
    int lane = threadIdx.x & 63;
    if (w >= n_nodes) return;
    int s = row_start[w], e = row_start[w + 1];
    int col = lane * VEC;
    float acc[4][VEC];
#pragma unroll
    for (int c = 0; c < 4; ++c)
#pragma unroll
        for (int j = 0; j < VEC; ++j) acc[c][j] = 0.f;
    int i = s;
    for (; i + 7 < e; i += 8) {
        int u[8];
#pragma unroll
        for (int j = 0; j < 8; ++j) u[j] = edge_src[i + j];
        typename RawT<VEC>::T r[8];
#pragma unroll
        for (int j = 0; j < 8; ++j) r[j] = load_raw<VEC>(tmp + (size_t)u[j] * dim + col);
#pragma unroll
        for (int j = 0; j < 8; ++j) add_raw<VEC>(acc[j & 3], r[j]);
    }
    for (; i + 3 < e; i += 4) {
        int u0 = edge_src[i];
        int u1 = edge_src[i + 1];
        int u2 = edge_src[i + 2];
        int u3 = edge_src[i + 3];
        load_add<VEC>(acc[0], tmp + (size_t)u0 * dim + col);
        load_add<VEC>(acc[1], tmp + (size_t)u1 * dim + col);
        load_add<VEC>(acc[2], tmp + (size_t)u2 * dim + col);
        load_add<VEC>(acc[3], tmp + (size_t)u3 * dim + col);
    }
    for (; i < e; ++i) {
        int u = edge_src[i];
        load_add<VEC>(acc[0], tmp + (size_t)u * dim + col);
    }
    float d = nd[w];
    float r[VEC];
#pragma unroll
    for (int j = 0; j < VEC; ++j) {
        float v = fmaf((acc[0][j] + acc[1][j]) + (acc[2][j] + acc[3][j]), d, bias[col + j]);
        r[j] = RELU ? fmaxf(v, 0.f) : v;
    }
    size_t base = (size_t)w * dim + col;
    if (OUT_MODE != 1) {
        if (VEC == 4) {
            *(float4*)(outF + base) = make_float4(r[0], r[1], r[2], r[3]);
        } else if (VEC == 2) {
            *(float2*)(outF + base) = make_float2(r[0], r[1]);
        } else {
            outF[base] = r[0];
        }
    }
    if (OUT_MODE != 0) {
        ushort_t h[VEC], l[VEC];
#pragma unroll
        for (int j = 0; j < VEC; ++j) split1(r[j], h[j], l[j]);
        if (VEC == 4) {
            *(ushort4*)(outH + base) = make_ushort4(h[0], h[1], h[2], h[3]);
            *(ushort4*)(outL + base) = make_ushort4(l[0], l[1], l[2], l[3]);
        } else if (VEC == 2) {
            *(ushort2*)(outH + base) = make_ushort2(h[0], h[1]);
            *(ushort2*)(outL + base) = make_ushort2(l[0], l[1]);
        } else {
            outH[base] = h[0];
            outL[base] = l[0];
        }
    }
}

extern "C" void kernel_launch(void* const* d_in, const int* in_sizes, int n_in,
                              void* d_out, int out_size, void* d_ws, size_t ws_size,
                              hipStream_t stream) {
    const float* features = (const float*)d_in[0];
    const int* src = (const int*)d_in[1];
    const int* dst = (const int*)d_in[2];
    const float* W0 = (const float*)d_in[3];
    const float* b0 = (const float*)d_in[4];
    const float* W1 = (const float*)d_in[5];
    const float* b1 = (const float*)d_in[6];
    const float* W2 = (const float*)d_in[7];
    const float* b2 = (const float*)d_in[8];
    const float* W3 = (const float*)d_in[9];
    const float* b3 = (const float*)d_in[10];
    float* out = (float*)d_out;

    // workspace carve (~160 MB)
    char* p = (char*)d_ws;
    auto alloc = [&](size_t bytes) {
        void* r = (void*)p;
        p += (bytes + 255) & ~(size_t)255;
        return r;
    };
    __half* tmp = (__half*)alloc((size_t)N_NODES * 256 * 2);        // 25.6 MB GEMM out (fp16)
    ushort_t* H1hi = (ushort_t*)alloc((size_t)N_NODES * 256 * 2);   // [M][256]
    ushort_t* H1lo = (ushort_t*)alloc((size_t)N_NODES * 256 * 2);
    ushort_t* H2hi = (ushort_t*)alloc((size_t)N_NODES * 256 * 2);   // [M][256]
    ushort_t* H2lo = (ushort_t*)alloc((size_t)N_NODES * 256 * 2);
    ushort_t* H3hi = (ushort_t*)alloc((size_t)N_NODES * 128 * 2);   // [M][128]
    ushort_t* H3lo = (ushort_t*)alloc((size_t)N_NODES * 128 * 2);
    ushort_t* W0hi = (ushort_t*)alloc(512 * 256 * 2);               // Wt planes [N][K]
    ushort_t* W0lo = (ushort_t*)alloc(512 * 256 * 2);
    ushort_t* W1hi = (ushort_t*)alloc(256 * 256 * 2);
    ushort_t* W1lo = (ushort_t*)alloc(256 * 256 * 2);
    ushort_t* W2hi = (ushort_t*)alloc(256 * 128 * 2);
    ushort_t* W2lo = (ushort_t*)alloc(256 * 128 * 2);
    ushort_t* W3hi = (ushort_t*)alloc(128 * 64 * 2);
    ushort_t* W3lo = (ushort_t*)alloc(128 * 64 * 2);
    int* edge_src = (int*)alloc((size_t)N_EDGES * 4);
    int* row_start = (int*)alloc((size_t)(N_NODES + 1) * 4);
    int* cursor = (int*)alloc((size_t)N_NODES * 4);
    int* degO = (int*)alloc((size_t)N_NODES * 4);
    int* degI = (int*)alloc((size_t)N_NODES * 4);
    int* bsum = (int*)alloc(64 * 4);
    float* ns = (float*)alloc((size_t)N_NODES * 4);
    float* nd = (float*)alloc((size_t)N_NODES * 4);

    // ---- graph preprocessing ----
    hipMemsetAsync(degO, 0, (size_t)N_NODES * 4, stream);
    hipMemsetAsync(degI, 0, (size_t)N_NODES * 4, stream);
    count_deg_k<<<(N_EDGES + 255) / 256, 256, 0, stream>>>(src, dst, N_EDGES, degO, degI);
    norm_k<<<(N_NODES + 255) / 256, 256, 0, stream>>>(degO, degI, ns, nd, N_NODES);
    {
        const int nb = (N_NODES + 1023) / 1024;  // 49
        scan_local_k<<<nb, 1024, 0, stream>>>(degI, row_start, bsum, N_NODES);
        scan_bsum_k<<<1, 64, 0, stream>>>(bsum, row_start + N_NODES, nb);
        scan_add_k<<<(N_NODES + 255) / 256, 256, 0, stream>>>(row_start, cursor, bsum, N_NODES);
    }
    fill_csr_k<<<(N_EDGES + 255) / 256, 256, 0, stream>>>(src, dst, N_EDGES, cursor, edge_src);

    // ---- weight splits (one launch) ----
    {
        const int tot = 512 * 256 + 256 * 256 + 256 * 128 + 128 * 64;
        split_weights_k<<<(tot + 255) / 256, 256, 0, stream>>>(
            W0, W1, W2, W3, W0hi, W0lo, W1hi, W1lo, W2hi, W2lo, W3hi, W3lo);
    }

    const int gm = (N_NODES + 127) / 128;     // 391 blocks, BM=128
    const int aggBlocks = (N_NODES + 3) / 4;  // 4 waves/block

    // ---- layer 0: 512 -> 256 (feature split fused into staging, pipelined) ----
    gemm_mfma_k<128, 1><<<dim3(gm, 2), 256, 0, stream>>>(features, nullptr, nullptr,
                                                         W0hi, W0lo, tmp, N_NODES, 512, 256, ns);
    agg_ep_k<4, 1, 1><<<aggBlocks, 256, 0, stream>>>(tmp, nullptr, H1hi, H1lo, row_start,
                                                     edge_src, nd, b0, N_NODES, 256);

    // ---- layer 1: 256 -> 256 ----
    gemm_mfma_k<128, 0><<<dim3(gm, 2), 256, 0, stream>>>(nullptr, H1hi, H1lo, W1hi, W1lo,
                                                         tmp, N_NODES, 256, 256, ns);
    agg_ep_k<4, 1, 1><<<aggBlocks, 256, 0, stream>>>(tmp, nullptr, H2hi, H2lo, row_start,
                                                     edge_src, nd, b1, N_NODES, 256);

    // ---- layer 2: 256 -> 128 (aspect_embed -> d_out, planes for L3) ----
    gemm_mfma_k<128, 0><<<dim3(gm, 1), 256, 0, stream>>>(nullptr, H2hi, H2lo, W2hi, W2lo,
                                                         tmp, N_NODES, 256, 128, ns);
    agg_ep_k<2, 0, 2><<<aggBlocks, 256, 0, stream>>>(tmp, out, H3hi, H3lo, row_start,
                                                     edge_src, nd, b2, N_NODES, 128);

    // ---- layer 3: 128 -> 64 (h -> d_out + 50000*128) ----
    gemm_mfma_k<64, 0><<<dim3(gm, 1), 256, 0, stream>>>(nullptr, H3hi, H3lo, W3hi, W3lo,
                                                        tmp, N_NODES, 128, 64, ns);
    agg_ep_k<1, 0, 0><<<aggBlocks, 256, 0, stream>>>(tmp, out + (size_t)N_NODES * 128,
                                                     nullptr, nullptr, row_start, edge_src,
                                                     nd, b3, N_NODES, 64);
}

// Round 5
// 576.387 us; speedup vs baseline: 1.1321x; 1.0193x over previous
//
#include <hip/hip_runtime.h>
#include <hip/hip_bf16.h>
#include <hip/hip_fp16.h>

#define N_NODES 50000
#define N_EDGES 800000

typedef unsigned short ushort_t;
typedef unsigned int uint_t;
typedef __attribute__((ext_vector_type(8))) short short8;
typedef __attribute__((ext_vector_type(4))) float f32x4;

// ---------------- bf16 split helpers ----------------
__device__ inline ushort_t bf16_rne(float x) {
    uint_t u = __float_as_uint(x);
    uint_t r = (u + 0x7fffu + ((u >> 16) & 1u)) >> 16;
    return (ushort_t)r;
}
__device__ inline void split1(float x, ushort_t& h, ushort_t& l) {
    ushort_t hh = bf16_rne(x);
    float fh = __uint_as_float((uint_t)hh << 16);
    h = hh;
    l = bf16_rne(x - fh);
}

// ---------------- async global->LDS (16B per lane, wave-uniform LDS base) ----
__device__ inline void gl_lds16(const void* g, void* l) {
    __builtin_amdgcn_global_load_lds(
        (const __attribute__((address_space(1))) unsigned int*)g,
        (__attribute__((address_space(3))) unsigned int*)l, 16, 0, 0);
}

// ---------------- degree count ----------------
__global__ void count_deg_k(const int* __restrict__ src, const int* __restrict__ dst,
                            int n_edges, int* __restrict__ deg_out, int* __restrict__ deg_in) {
    int i = blockIdx.x * blockDim.x + threadIdx.x;
    if (i < n_edges) {
        atomicAdd(&deg_out[src[i]], 1);
        atomicAdd(&deg_in[dst[i]], 1);
    }
}

// ---------------- norms ----------------
__global__ void norm_k(const int* __restrict__ deg_out, const int* __restrict__ deg_in,
                       float* __restrict__ ns, float* __restrict__ nd, int n) {
    int i = blockIdx.x * blockDim.x + threadIdx.x;
    if (i < n) {
        ns[i] = 1.0f / sqrtf((float)max(deg_out[i], 1));
        nd[i] = 1.0f / sqrtf((float)max(deg_in[i], 1));
    }
}

// ---------------- parallel exclusive scan (3 kernels) ----------------
__global__ void scan_local_k(const int* __restrict__ deg, int* __restrict__ row_start,
                             int* __restrict__ bsum, int n) {
    __shared__ int wexcl[16];
    const int tid = threadIdx.x;
    const int lane = tid & 63, wid = tid >> 6;
    const int i = blockIdx.x * 1024 + tid;
    int v = (i < n) ? deg[i] : 0;
    int x = v;
#pragma unroll
    for (int off = 1; off < 64; off <<= 1) {
        int y = __shfl_up(x, off, 64);
        if (lane >= off) x += y;
    }
    if (lane == 63) wexcl[wid] = x;
    __syncthreads();
    if (wid == 0) {
        int tv = (lane < 16) ? wexcl[lane] : 0;
        int xs = tv;
#pragma unroll
        for (int off = 1; off < 16; off <<= 1) {
            int y = __shfl_up(xs, off, 64);
            if (lane >= off) xs += y;
        }
        if (lane < 16) wexcl[lane] = xs - tv;
    }
    __syncthreads();
    int excl = wexcl[wid] + x - v;
    if (i < n) row_start[i] = excl;
    if (tid == 1023) bsum[blockIdx.x] = excl + v;
}
__global__ void scan_bsum_k(int* __restrict__ bsum, int* __restrict__ total, int nb) {
    int lane = threadIdx.x;
    int v = (lane < nb) ? bsum[lane] : 0;
    int x = v;
#pragma unroll
    for (int off = 1; off < 64; off <<= 1) {
        int y = __shfl_up(x, off, 64);
        if (lane >= off) x += y;
    }
    if (lane < nb) bsum[lane] = x - v;
    if (lane == 63) *total = x;
}
__global__ void scan_add_k(int* __restrict__ row_start, int* __restrict__ cursor,
                           const int* __restrict__ bsum, int n) {
    int i = blockIdx.x * blockDim.x + threadIdx.x;
    if (i < n) {
        int o = row_start[i] + bsum[i >> 10];
        row_start[i] = o;
        cursor[i] = o;
    }
}

// ---------------- CSR fill ----------------
__global__ void fill_csr_k(const int* __restrict__ src, const int* __restrict__ dst,
                           int n_edges, int* __restrict__ cursor, int* __restrict__ edge_src) {
    int i = blockIdx.x * blockDim.x + threadIdx.x;
    if (i < n_edges) {
        int pos = atomicAdd(&cursor[dst[i]], 1);
        edge_src[pos] = src[i];
    }
}

// ---------------- split+transpose all 4 weights in one launch ----------------
__global__ void split_weights_k(const float* __restrict__ W0, const float* __restrict__ W1,
                                const float* __restrict__ W2, const float* __restrict__ W3,
                                ushort_t* __restrict__ W0h, ushort_t* __restrict__ W0l,
                                ushort_t* __restrict__ W1h, ushort_t* __restrict__ W1l,
                                ushort_t* __restrict__ W2h, ushort_t* __restrict__ W2l,
                                ushort_t* __restrict__ W3h, ushort_t* __restrict__ W3l) {
    const int s0 = 512 * 256, s1 = s0 + 256 * 256, s2 = s1 + 256 * 128, s3 = s2 + 128 * 64;
    int idx = blockIdx.x * blockDim.x + threadIdx.x;
    const float* W;
    ushort_t *H, *L;
    int K, N, local;
    if (idx < s0) { W = W0; H = W0h; L = W0l; K = 512; N = 256; local = idx; }
    else if (idx < s1) { W = W1; H = W1h; L = W1l; K = 256; N = 256; local = idx - s0; }
    else if (idx < s2) { W = W2; H = W2h; L = W2l; K = 256; N = 128; local = idx - s1; }
    else if (idx < s3) { W = W3; H = W3h; L = W3l; K = 128; N = 64; local = idx - s2; }
    else return;
    int n = local / K;
    int k = local - n * K;
    split1(W[(size_t)k * N + n], H[local], L[local]);
}

// ---------------- MFMA GEMM: C[M,N] = fp16( ns[row] * (A @ W) ), bf16x2 3-pass ----
// ASRC=0: A/B planes staged via global_load_lds with DOUBLE-BUFFERED LDS
//         (stage t+1 before computing t; one barrier per K-step).
// ASRC=1: SINGLE-buffer (round-3 structure, empirically best): B-DMA issue +
//         split of reg-prefetched fp32 A share the stage phase; next-step fp32
//         loads issued right after the barrier so HBM latency hides under MFMA.
// LDS layout linear in chunk order: chunk c (row c>>2, k-octet c&3) at bytes [16c,16c+16).
template <int BN, int ASRC>  // BN: 128 or 64
__global__ __launch_bounds__(256) void gemm_mfma_k(
    const float* __restrict__ Af,
    const ushort_t* __restrict__ Ahi, const ushort_t* __restrict__ Alo,
    const ushort_t* __restrict__ Bhi, const ushort_t* __restrict__ Blo,
    __half* __restrict__ C, int M, int K, int N, const float* __restrict__ ns) {
    constexpr int BM = 128, BK = 32;
    constexpr int WN = (BN == 128) ? 2 : 1;
    constexpr int TM = BM / ((4 / WN) * 16);
    constexpr int TN = BN / (WN * 16);
    constexpr int NBUF = (ASRC == 0) ? 2 : 1;  // dbuf only for pure-DMA staging
    __shared__ __attribute__((aligned(16))) ushort_t Ah[NBUF][BM * BK];
    __shared__ __attribute__((aligned(16))) ushort_t Al[NBUF][BM * BK];
    __shared__ __attribute__((aligned(16))) ushort_t Bh[NBUF][BN * BK];
    __shared__ __attribute__((aligned(16))) ushort_t Bl[NBUF][BN * BK];
    const int t = threadIdx.x;
    const int wave = t >> 6, lane = t & 63;
    const int quad = lane >> 4, l16 = lane & 15;
    const int m0 = blockIdx.x * BM, n0 = blockIdx.y * BN;
    const int wrow = (wave / WN) * (TM * 16);
    const int wcol = (wave % WN) * (TN * 16);

    f32x4 acc[TM][TN];
#pragma unroll
    for (int mi = 0; mi < TM; ++mi)
#pragma unroll
        for (int ni = 0; ni < TN; ++ni) acc[mi][ni] = (f32x4){0.f, 0.f, 0.f, 0.f};

    auto stageB = [&](int k0, int buf) {
#pragma unroll
        for (int j = 0; j < BN / 64; ++j) {
            int cg = wave * (BN / 64) + j;
            int c = cg * 64 + lane;
            int r = c >> 2, q = c & 3;
            size_t goff = (size_t)(n0 + r) * K + k0 + q * 8;
            gl_lds16(Bhi + goff, &Bh[buf][cg * 512]);
            gl_lds16(Blo + goff, &Bl[buf][cg * 512]);
        }
    };
    auto stageA_dma = [&](int k0, int buf) {
#pragma unroll
        for (int j = 0; j < 2; ++j) {
            int cg = wave * 2 + j;
            int c = cg * 64 + lane;
            int r = c >> 2, q = c & 3;
            int gr = m0 + r;
            if (gr >= M) gr = M - 1;
            size_t goff = (size_t)gr * K + k0 + q * 8;
            gl_lds16(Ahi + goff, &Ah[buf][cg * 512]);
            gl_lds16(Alo + goff, &Al[buf][cg * 512]);
        }
    };
    // ASRC=1 register prefetch (statically indexed)
    float4 pv[2][2];
    auto loadA = [&](int kq) {
#pragma unroll
        for (int j = 0; j < 2; ++j) {
            int c = t + j * 256;
            int r = c >> 2, q = c & 3;
            int gr = m0 + r;
            if (gr >= M) gr = M - 1;
            const float* ap = Af + (size_t)gr * K + kq + q * 8;
            pv[j][0] = *(const float4*)ap;
            pv[j][1] = *(const float4*)(ap + 4);
        }
    };
    auto splitA = [&](int buf) {
#pragma unroll
        for (int j = 0; j < 2; ++j) {
            int c = t + j * 256;
            float vv[8] = {pv[j][0].x, pv[j][0].y, pv[j][0].z, pv[j][0].w,
                           pv[j][1].x, pv[j][1].y, pv[j][1].z, pv[j][1].w};
            short8 hh, ll;
#pragma unroll
            for (int ee = 0; ee < 8; ++ee) {
                ushort_t h, l;
                split1(vv[ee], h, l);
                hh[ee] = (short)h;
                ll[ee] = (short)l;
            }
            *(short8*)&Ah[buf][c * 8] = hh;
            *(short8*)&Al[buf][c * 8] = ll;
        }
    };
    auto compute = [&](int buf) {
        short8 afh[TM], afl[TM], bfh[TN], bfl[TN];
#pragma unroll
        for (int mi = 0; mi < TM; ++mi) {
            int m = wrow + mi * 16 + l16;
            afh[mi] = *(const short8*)&Ah[buf][m * BK + quad * 8];
            afl[mi] = *(const short8*)&Al[buf][m * BK + quad * 8];
        }
#pragma unroll
        for (int ni = 0; ni < TN; ++ni) {
            int n = wcol + ni * 16 + l16;
            bfh[ni] = *(const short8*)&Bh[buf][n * BK + quad * 8];
            bfl[ni] = *(const short8*)&Bl[buf][n * BK + quad * 8];
        }
#pragma unroll
        for (int mi = 0; mi < TM; ++mi)
#pragma unroll
            for (int ni = 0; ni < TN; ++ni) {
                acc[mi][ni] = __builtin_amdgcn_mfma_f32_16x16x32_bf16(afh[mi], bfh[ni],
                                                                      acc[mi][ni], 0, 0, 0);
                acc[mi][ni] = __builtin_amdgcn_mfma_f32_16x16x32_bf16(afh[mi], bfl[ni],
                                                                      acc[mi][ni], 0, 0, 0);
                acc[mi][ni] = __builtin_amdgcn_mfma_f32_16x16x32_bf16(afl[mi], bfh[ni],
                                                                      acc[mi][ni], 0, 0, 0);
            }
    };

    if (ASRC == 0) {
        // ---- pipelined dbuf: stage t+1 before computing t; one barrier/step
        stageB(0, 0);
        stageA_dma(0, 0);
        __syncthreads();
        int cur = 0;
        for (int k0 = 0; k0 < K; k0 += BK) {
            const int nxt = cur ^ 1;
            if (k0 + BK < K) {
                stageB(k0 + BK, nxt % NBUF);
                stageA_dma(k0 + BK, nxt % NBUF);
            }
            compute(cur);
            __syncthreads();
            cur = nxt % NBUF;
        }
    } else {
        // ---- single-buffer with A-register prefetch (round-3 structure)
        loadA(0);
        for (int k0 = 0; k0 < K; k0 += BK) {
            stageB(k0, 0);   // DMA flies during splitA
            splitA(0);       // consume pv (this step's data)
            __syncthreads();
            if (k0 + BK < K) loadA(k0 + BK);  // latency hides under MFMA phase
            compute(0);
            __syncthreads();
        }
    }
    // ---- epilogue: C/D layout col=l16, row=quad*4+reg; scale by ns, emit fp16
#pragma unroll
    for (int mi = 0; mi < TM; ++mi)
#pragma unroll
        for (int r = 0; r < 4; ++r) {
            int row = m0 + wrow + mi * 16 + quad * 4 + r;
            if (row < M) {
                float s = ns[row];
#pragma unroll
                for (int ni = 0; ni < TN; ++ni) {
                    C[(size_t)row * N + n0 + wcol + ni * 16 + l16] =
                        __float2half(acc[mi][ni][r] * s);
                }
            }
        }
}

// ---------------- gather-row raw load/accumulate helpers (32-lane rows) ------
template <int VEC> struct RawT;
template <> struct RawT<8> { using T = uint4; };
template <> struct RawT<4> { using T = uint2; };
template <> struct RawT<2> { using T = uint_t; };

template <int VEC>
__device__ inline typename RawT<VEC>::T load_raw(const __half* p) {
    return *(const typename RawT<VEC>::T*)p;
}
__device__ inline void add_h2(float* a, uint_t w) {
    __half2 h = *reinterpret_cast<__half2*>(&w);
    float2 f = __half22float2(h);
    a[0] += f.x;
    a[1] += f.y;
}
template <int VEC>
__device__ inline void add_raw(float* a, typename RawT<VEC>::T r) {
    if (VEC == 8) {
        uint4 v = *(uint4*)&r;
        add_h2(a + 0, v.x); add_h2(a + 2, v.y); add_h2(a + 4, v.z); add_h2(a + 6, v.w);
    } else if (VEC == 4) {
        uint2 v = *(uint2*)&r;
        add_h2(a + 0, v.x); add_h2(a + 2, v.y);
    } else {
        uint_t v = *(uint_t*)&r;
        add_h2(a, v);
    }
}
template <int VEC>
__device__ inline void load_add(float* a, const __half* p) {
    add_raw<VEC>(a, load_raw<VEC>(p));
}

// ---------------- CSR aggregation + fused epilogue ----------------
// One node per 32-lane HALF-WAVE; lane covers VEC consecutive cols (dim = 32*VEC).
// res = act(nd[w] * sum_{e: dst==w} tmp[src[e]] + bias)
// OUT_MODE: 0 = fp32 only, 1 = hi/lo planes only, 2 = both
// Per-column edge-accumulation order identical to previous versions -> bit-identical.
template <int VEC, int RELU, int OUT_MODE>
__global__ void agg_ep_k(const __half* __restrict__ tmp, float* __restrict__ outF,
                         ushort_t* __restrict__ outH, ushort_t* __restrict__ outL,
                         const int* __restrict__ row_start, const int* __restrict__ edge_src,
                         const float* __restrict__ nd, const float* __restrict__ bias,
                         int n_nodes, int dim) {
    int w = (blockIdx.x * blockDim.x + threadIdx.x) >> 5;
    int lane = threadIdx.x & 31;
    if (w >= n_nodes) return;
    int s = row_start[w], e = row_start[w + 1];
    int col = lane * VEC;
    float acc[4][VEC];
#pragma unroll
    for (int c = 0; c < 4; ++c)
#pragma unroll
        for (int j = 0; j < VEC; ++j) acc[c][j] = 0.f;
    int i = s;
    for (; i + 7 < e; i += 8) {
        int u[8];
#pragma unroll
        for (int j = 0; j < 8; ++j) u[j] = edge_src[i + j];
        typename RawT<VEC>::T r[8];
#pragma unroll
        for (int j = 0; j < 8; ++j) r[j] = load_raw<VEC>(tmp + (size_t)u[j] * dim + col);
#pragma unroll
        for (int j = 0; j < 8; ++j) add_raw<VEC>(acc[j & 3], r[j]);
    }
    for (; i + 3 < e; i += 4) {
        int u0 = edge_src[i];
        int u1 = edge_src[i + 1];
        int u2 = edge_src[i + 2];
        int u3 = edge_src[i + 3];
        load_add<VEC>(acc[0], tmp + (size_t)u0 * dim + col);
        load_add<VEC>(acc[1], tmp + (size_t)u1 * dim + col);
        load_add<VEC>(acc[2], tmp + (size_t)u2 * dim + col);
        load_add<VEC>(acc[3], tmp + (size_t)u3 * dim + col);
    }
    for (; i < e; ++i) {
        int u = edge_src[i];
        load_add<VEC>(acc[0], tmp + (size_t)u * dim + col);
    }
    float d = nd[w];
    float r[VEC];
#pragma unroll
    for (int j = 0; j < VEC; ++j) {
        float v = fmaf((acc[0][j] + acc[1][j]) + (acc[2][j] + acc[3][j]), d, bias[col + j]);
        r[j] = RELU ? fmaxf(v, 0.f) : v;
    }
    size_t base = (size_t)w * dim + col;
    if (OUT_MODE != 1) {
        if (VEC == 8) {
            *(float4*)(outF + base) = make_float4(r[0], r[1], r[2], r[3]);
            *(float4*)(outF + base + 4) = make_float4(r[4], r[5], r[6], r[7]);
        } else if (VEC == 4) {
            *(float4*)(outF + base) = make_float4(r[0], r[1], r[2], r[3]);
        } else {
            *(float2*)(outF + base) = make_float2(r[0], r[1]);
        }
    }
    if (OUT_MODE != 0) {
        ushort_t h[VEC], l[VEC];
#pragma unroll
        for (int j = 0; j < VEC; ++j) split1(r[j], h[j], l[j]);
        if (VEC == 8) {
            short8 hv, lv;
#pragma unroll
            for (int j = 0; j < 8; ++j) { hv[j] = (short)h[j]; lv[j] = (short)l[j]; }
            *(short8*)(outH + base) = hv;
            *(short8*)(outL + base) = lv;
        } else if (VEC == 4) {
            *(ushort4*)(outH + base) = make_ushort4(h[0], h[1], h[2], h[3]);
            *(ushort4*)(outL + base) = make_ushort4(l[0], l[1], l[2], l[3]);
        } else {
            *(ushort2*)(outH + base) = make_ushort2(h[0], h[1]);
            *(ushort2*)(outL + base) = make_ushort2(l[0], l[1]);
        }
    }
}

extern "C" void kernel_launch(void* const* d_in, const int* in_sizes, int n_in,
                              void* d_out, int out_size, void* d_ws, size_t ws_size,
                              hipStream_t stream) {
    const float* features = (const float*)d_in[0];
    const int* src = (const int*)d_in[1];
    const int* dst = (const int*)d_in[2];
    const float* W0 = (const float*)d_in[3];
    const float* b0 = (const float*)d_in[4];
    const float* W1 = (const float*)d_in[5];
    const float* b1 = (const float*)d_in[6];
    const float* W2 = (const float*)d_in[7];
    const float* b2 = (const float*)d_in[8];
    const float* W3 = (const float*)d_in[9];
    const float* b3 = (const float*)d_in[10];
    float* out = (float*)d_out;

    // workspace carve (~160 MB)
    char* p = (char*)d_ws;
    auto alloc = [&](size_t bytes) {
        void* r = (void*)p;
        p += (bytes + 255) & ~(size_t)255;
        return r;
    };
    __half* tmp = (__half*)alloc((size_t)N_NODES * 256 * 2);        // 25.6 MB GEMM out (fp16)
    ushort_t* H1hi = (ushort_t*)alloc((size_t)N_NODES * 256 * 2);   // [M][256]
    ushort_t* H1lo = (ushort_t*)alloc((size_t)N_NODES * 256 * 2);
    ushort_t* H2hi = (ushort_t*)alloc((size_t)N_NODES * 256 * 2);   // [M][256]
    ushort_t* H2lo = (ushort_t*)alloc((size_t)N_NODES * 256 * 2);
    ushort_t* H3hi = (ushort_t*)alloc((size_t)N_NODES * 128 * 2);   // [M][128]
    ushort_t* H3lo = (ushort_t*)alloc((size_t)N_NODES * 128 * 2);
    ushort_t* W0hi = (ushort_t*)alloc(512 * 256 * 2);               // Wt planes [N][K]
    ushort_t* W0lo = (ushort_t*)alloc(512 * 256 * 2);
    ushort_t* W1hi = (ushort_t*)alloc(256 * 256 * 2);
    ushort_t* W1lo = (ushort_t*)alloc(256 * 256 * 2);
    ushort_t* W2hi = (ushort_t*)alloc(256 * 128 * 2);
    ushort_t* W2lo = (ushort_t*)alloc(256 * 128 * 2);
    ushort_t* W3hi = (ushort_t*)alloc(128 * 64 * 2);
    ushort_t* W3lo = (ushort_t*)alloc(128 * 64 * 2);
    int* edge_src = (int*)alloc((size_t)N_EDGES * 4);
    int* row_start = (int*)alloc((size_t)(N_NODES + 1) * 4);
    int* cursor = (int*)alloc((size_t)N_NODES * 4);
    int* degO = (int*)alloc((size_t)N_NODES * 4);
    int* degI = (int*)alloc((size_t)N_NODES * 4);
    int* bsum = (int*)alloc(64 * 4);
    float* ns = (float*)alloc((size_t)N_NODES * 4);
    float* nd = (float*)alloc((size_t)N_NODES * 4);

    // ---- graph preprocessing ----
    hipMemsetAsync(degO, 0, (size_t)N_NODES * 4, stream);
    hipMemsetAsync(degI, 0, (size_t)N_NODES * 4, stream);
    count_deg_k<<<(N_EDGES + 255) / 256, 256, 0, stream>>>(src, dst, N_EDGES, degO, degI);
    norm_k<<<(N_NODES + 255) / 256, 256, 0, stream>>>(degO, degI, ns, nd, N_NODES);
    {
        const int nb = (N_NODES + 1023) / 1024;  // 49
        scan_local_k<<<nb, 1024, 0, stream>>>(degI, row_start, bsum, N_NODES);
        scan_bsum_k<<<1, 64, 0, stream>>>(bsum, row_start + N_NODES, nb);
        scan_add_k<<<(N_NODES + 255) / 256, 256, 0, stream>>>(row_start, cursor, bsum, N_NODES);
    }
    fill_csr_k<<<(N_EDGES + 255) / 256, 256, 0, stream>>>(src, dst, N_EDGES, cursor, edge_src);

    // ---- weight splits (one launch) ----
    {
        const int tot = 512 * 256 + 256 * 256 + 256 * 128 + 128 * 64;
        split_weights_k<<<(tot + 255) / 256, 256, 0, stream>>>(
            W0, W1, W2, W3, W0hi, W0lo, W1hi, W1lo, W2hi, W2lo, W3hi, W3lo);
    }

    const int gm = (N_NODES + 127) / 128;     // 391 blocks, BM=128
    const int aggBlocks = (N_NODES + 7) / 8;  // 8 nodes/block (32-lane halves)

    // ---- layer 0: 512 -> 256 (feature split fused into staging, single-buf) ----
    gemm_mfma_k<128, 1><<<dim3(gm, 2), 256, 0, stream>>>(features, nullptr, nullptr,
                                                         W0hi, W0lo, tmp, N_NODES, 512, 256, ns);
    agg_ep_k<8, 1, 1><<<aggBlocks, 256, 0, stream>>>(tmp, nullptr, H1hi, H1lo, row_start,
                                                     edge_src, nd, b0, N_NODES, 256);

    // ---- layer 1: 256 -> 256 (dbuf DMA pipeline) ----
    gemm_mfma_k<128, 0><<<dim3(gm, 2), 256, 0, stream>>>(nullptr, H1hi, H1lo, W1hi, W1lo,
                                                         tmp, N_NODES, 256, 256, ns);
    agg_ep_k<8, 1, 1><<<aggBlocks, 256, 0, stream>>>(tmp, nullptr, H2hi, H2lo, row_start,
                                                     edge_src, nd, b1, N_NODES, 256);

    // ---- layer 2: 256 -> 128 (aspect_embed -> d_out, planes for L3) ----
    gemm_mfma_k<128, 0><<<dim3(gm, 1), 256, 0, stream>>>(nullptr, H2hi, H2lo, W2hi, W2lo,
                                                         tmp, N_NODES, 256, 128, ns);
    agg_ep_k<4, 0, 2><<<aggBlocks, 256, 0, stream>>>(tmp, out, H3hi, H3lo, row_start,
                                                     edge_src, nd, b2, N_NODES, 128);

    // ---- layer 3: 128 -> 64 (h -> d_out + 50000*128) ----
    gemm_mfma_k<64, 0><<<dim3(gm, 1), 256, 0, stream>>>(nullptr, H3hi, H3lo, W3hi, W3lo,
                                                        tmp, N_NODES, 128, 64, ns);
    agg_ep_k<2, 0, 0><<<aggBlocks, 256, 0, stream>>>(tmp, out + (size_t)N_NODES * 128,
                                                     nullptr, nullptr, row_start, edge_src,
                                                     nd, b3, N_NODES, 64);
}

// Round 6
// 545.807 us; speedup vs baseline: 1.1955x; 1.0560x over previous
//
#include <hip/hip_runtime.h>
#include <hip/hip_bf16.h>
#include <hip/hip_fp16.h>

#define N_NODES 50000
#define N_EDGES 800000

typedef unsigned short ushort_t;
typedef unsigned int uint_t;
typedef __attribute__((ext_vector_type(8))) short short8;
typedef __attribute__((ext_vector_type(4))) float f32x4;

// ---------------- bf16 split helpers ----------------
// Native RNE converts (backend emits v_cvt_pk_bf16_f32 for pairs); rounding is
// identical to the previous integer bf16_rne (both RNE on the same fp32 values)
// -> bit-identical results.
__device__ inline void split1(float x, ushort_t& h, ushort_t& l) {
    __hip_bfloat16 hb = __float2bfloat16(x);
    float fh = __bfloat162float(hb);
    __hip_bfloat16 lb = __float2bfloat16(x - fh);
    h = __builtin_bit_cast(ushort_t, hb);
    l = __builtin_bit_cast(ushort_t, lb);
}

// ---------------- async global->LDS (16B per lane, wave-uniform LDS base) ----
__device__ inline void gl_lds16(const void* g, void* l) {
    __builtin_amdgcn_global_load_lds(
        (const __attribute__((address_space(1))) unsigned int*)g,
        (__attribute__((address_space(3))) unsigned int*)l, 16, 0, 0);
}

// ---------------- degree count + edge rank ----------------
// erank[e] = this edge's arrival index within its dst bucket (the atomicAdd
// return that was previously discarded) -> fill_csr needs no atomics.
__global__ void count_deg_k(const int* __restrict__ src, const int* __restrict__ dst,
                            int n_edges, int* __restrict__ deg_out, int* __restrict__ deg_in,
                            int* __restrict__ erank) {
    int i = blockIdx.x * blockDim.x + threadIdx.x;
    if (i < n_edges) {
        atomicAdd(&deg_out[src[i]], 1);
        erank[i] = atomicAdd(&deg_in[dst[i]], 1);
    }
}

// ---------------- norms ----------------
__global__ void norm_k(const int* __restrict__ deg_out, const int* __restrict__ deg_in,
                       float* __restrict__ ns, float* __restrict__ nd, int n) {
    int i = blockIdx.x * blockDim.x + threadIdx.x;
    if (i < n) {
        ns[i] = 1.0f / sqrtf((float)max(deg_out[i], 1));
        nd[i] = 1.0f / sqrtf((float)max(deg_in[i], 1));
    }
}

// ---------------- parallel exclusive scan (3 kernels) ----------------
__global__ void scan_local_k(const int* __restrict__ deg, int* __restrict__ row_start,
                             int* __restrict__ bsum, int n) {
    __shared__ int wexcl[16];
    const int tid = threadIdx.x;
    const int lane = tid & 63, wid = tid >> 6;
    const int i = blockIdx.x * 1024 + tid;
    int v = (i < n) ? deg[i] : 0;
    int x = v;
#pragma unroll
    for (int off = 1; off < 64; off <<= 1) {
        int y = __shfl_up(x, off, 64);
        if (lane >= off) x += y;
    }
    if (lane == 63) wexcl[wid] = x;
    __syncthreads();
    if (wid == 0) {
        int tv = (lane < 16) ? wexcl[lane] : 0;
        int xs = tv;
#pragma unroll
        for (int off = 1; off < 16; off <<= 1) {
            int y = __shfl_up(xs, off, 64);
            if (lane >= off) xs += y;
        }
        if (lane < 16) wexcl[lane] = xs - tv;
    }
    __syncthreads();
    int excl = wexcl[wid] + x - v;
    if (i < n) row_start[i] = excl;
    if (tid == 1023) bsum[blockIdx.x] = excl + v;
}
__global__ void scan_bsum_k(int* __restrict__ bsum, int* __restrict__ total, int nb) {
    int lane = threadIdx.x;
    int v = (lane < nb) ? bsum[lane] : 0;
    int x = v;
#pragma unroll
    for (int off = 1; off < 64; off <<= 1) {
        int y = __shfl_up(x, off, 64);
        if (lane >= off) x += y;
    }
    if (lane < nb) bsum[lane] = x - v;
    if (lane == 63) *total = x;
}
__global__ void scan_add_k(int* __restrict__ row_start, const int* __restrict__ bsum, int n) {
    int i = blockIdx.x * blockDim.x + threadIdx.x;
    if (i < n) row_start[i] += bsum[i >> 10];
}

// ---------------- CSR fill (atomic-free scatter via precomputed rank) --------
__global__ void fill_csr_k(const int* __restrict__ src, const int* __restrict__ dst,
                           int n_edges, const int* __restrict__ row_start,
                           const int* __restrict__ erank, int* __restrict__ edge_src) {
    int i = blockIdx.x * blockDim.x + threadIdx.x;
    if (i < n_edges) {
        edge_src[row_start[dst[i]] + erank[i]] = src[i];
    }
}

// ---------------- split+transpose all 4 weights in one launch ----------------
__global__ void split_weights_k(const float* __restrict__ W0, const float* __restrict__ W1,
                                const float* __restrict__ W2, const float* __restrict__ W3,
                                ushort_t* __restrict__ W0h, ushort_t* __restrict__ W0l,
                                ushort_t* __restrict__ W1h, ushort_t* __restrict__ W1l,
                                ushort_t* __restrict__ W2h, ushort_t* __restrict__ W2l,
                                ushort_t* __restrict__ W3h, ushort_t* __restrict__ W3l) {
    const int s0 = 512 * 256, s1 = s0 + 256 * 256, s2 = s1 + 256 * 128, s3 = s2 + 128 * 64;
    int idx = blockIdx.x * blockDim.x + threadIdx.x;
    const float* W;
    ushort_t *H, *L;
    int K, N, local;
    if (idx < s0) { W = W0; H = W0h; L = W0l; K = 512; N = 256; local = idx; }
    else if (idx < s1) { W = W1; H = W1h; L = W1l; K = 256; N = 256; local = idx - s0; }
    else if (idx < s2) { W = W2; H = W2h; L = W2l; K = 256; N = 128; local = idx - s1; }
    else if (idx < s3) { W = W3; H = W3h; L = W3l; K = 128; N = 64; local = idx - s2; }
    else return;
    int n = local / K;
    int k = local - n * K;
    split1(W[(size_t)k * N + n], H[local], L[local]);
}

// ---------------- MFMA GEMM: C[M,N] = fp16( ns[row] * (A @ W) ), bf16x2 3-pass ----
// ASRC=0: A/B planes staged via global_load_lds with DOUBLE-BUFFERED LDS
//         (stage t+1 before computing t; one barrier per K-step).
// ASRC=1: SINGLE-buffer: B-DMA issue + split of reg-prefetched fp32 A share the
//         stage phase; next-step fp32 loads issued right after the barrier so
//         HBM latency hides under the MFMA phase.
// LDS layout linear in chunk order: chunk c (row c>>2, k-octet c&3) at bytes [16c,16c+16).
template <int BN, int ASRC>  // BN: 128 or 64
__global__ __launch_bounds__(256) void gemm_mfma_k(
    const float* __restrict__ Af,
    const ushort_t* __restrict__ Ahi, const ushort_t* __restrict__ Alo,
    const ushort_t* __restrict__ Bhi, const ushort_t* __restrict__ Blo,
    __half* __restrict__ C, int M, int K, int N, const float* __restrict__ ns) {
    constexpr int BM = 128, BK = 32;
    constexpr int WN = (BN == 128) ? 2 : 1;
    constexpr int TM = BM / ((4 / WN) * 16);
    constexpr int TN = BN / (WN * 16);
    constexpr int NBUF = (ASRC == 0) ? 2 : 1;  // dbuf only for pure-DMA staging
    __shared__ __attribute__((aligned(16))) ushort_t Ah[NBUF][BM * BK];
    __shared__ __attribute__((aligned(16))) ushort_t Al[NBUF][BM * BK];
    __shared__ __attribute__((aligned(16))) ushort_t Bh[NBUF][BN * BK];
    __shared__ __attribute__((aligned(16))) ushort_t Bl[NBUF][BN * BK];
    const int t = threadIdx.x;
    const int wave = t >> 6, lane = t & 63;
    const int quad = lane >> 4, l16 = lane & 15;
    const int m0 = blockIdx.x * BM, n0 = blockIdx.y * BN;
    const int wrow = (wave / WN) * (TM * 16);
    const int wcol = (wave % WN) * (TN * 16);

    f32x4 acc[TM][TN];
#pragma unroll
    for (int mi = 0; mi < TM; ++mi)
#pragma unroll
        for (int ni = 0; ni < TN; ++ni) acc[mi][ni] = (f32x4){0.f, 0.f, 0.f, 0.f};

    auto stageB = [&](int k0, int buf) {
#pragma unroll
        for (int j = 0; j < BN / 64; ++j) {
            int cg = wave * (BN / 64) + j;
            int c = cg * 64 + lane;
            int r = c >> 2, q = c & 3;
            size_t goff = (size_t)(n0 + r) * K + k0 + q * 8;
            gl_lds16(Bhi + goff, &Bh[buf][cg * 512]);
            gl_lds16(Blo + goff, &Bl[buf][cg * 512]);
        }
    };
    auto stageA_dma = [&](int k0, int buf) {
#pragma unroll
        for (int j = 0; j < 2; ++j) {
            int cg = wave * 2 + j;
            int c = cg * 64 + lane;
            int r = c >> 2, q = c & 3;
            int gr = m0 + r;
            if (gr >= M) gr = M - 1;
            size_t goff = (size_t)gr * K + k0 + q * 8;
            gl_lds16(Ahi + goff, &Ah[buf][cg * 512]);
            gl_lds16(Alo + goff, &Al[buf][cg * 512]);
        }
    };
    // ASRC=1 register prefetch (statically indexed)
    float4 pv[2][2];
    auto loadA = [&](int kq) {
#pragma unroll
        for (int j = 0; j < 2; ++j) {
            int c = t + j * 256;
            int r = c >> 2, q = c & 3;
            int gr = m0 + r;
            if (gr >= M) gr = M - 1;
            const float* ap = Af + (size_t)gr * K + kq + q * 8;
            pv[j][0] = *(const float4*)ap;
            pv[j][1] = *(const float4*)(ap + 4);
        }
    };
    auto splitA = [&](int buf) {
#pragma unroll
        for (int j = 0; j < 2; ++j) {
            int c = t + j * 256;
            float vv[8] = {pv[j][0].x, pv[j][0].y, pv[j][0].z, pv[j][0].w,
                           pv[j][1].x, pv[j][1].y, pv[j][1].z, pv[j][1].w};
            short8 hh, ll;
#pragma unroll
            for (int ee = 0; ee < 8; ++ee) {
                ushort_t h, l;
                split1(vv[ee], h, l);
                hh[ee] = (short)h;
                ll[ee] = (short)l;
            }
            *(short8*)&Ah[buf][c * 8] = hh;
            *(short8*)&Al[buf][c * 8] = ll;
        }
    };
    auto compute = [&](int buf) {
        short8 afh[TM], afl[TM], bfh[TN], bfl[TN];
#pragma unroll
        for (int mi = 0; mi < TM; ++mi) {
            int m = wrow + mi * 16 + l16;
            afh[mi] = *(const short8*)&Ah[buf][m * BK + quad * 8];
            afl[mi] = *(const short8*)&Al[buf][m * BK + quad * 8];
        }
#pragma unroll
        for (int ni = 0; ni < TN; ++ni) {
            int n = wcol + ni * 16 + l16;
            bfh[ni] = *(const short8*)&Bh[buf][n * BK + quad * 8];
            bfl[ni] = *(const short8*)&Bl[buf][n * BK + quad * 8];
        }
#pragma unroll
        for (int mi = 0; mi < TM; ++mi)
#pragma unroll
            for (int ni = 0; ni < TN; ++ni) {
                acc[mi][ni] = __builtin_amdgcn_mfma_f32_16x16x32_bf16(afh[mi], bfh[ni],
                                                                      acc[mi][ni], 0, 0, 0);
                acc[mi][ni] = __builtin_amdgcn_mfma_f32_16x16x32_bf16(afh[mi], bfl[ni],
                                                                      acc[mi][ni], 0, 0, 0);
                acc[mi][ni] = __builtin_amdgcn_mfma_f32_16x16x32_bf16(afl[mi], bfh[ni],
                                                                      acc[mi][ni], 0, 0, 0);
            }
    };

    if (ASRC == 0) {
        // ---- pipelined dbuf: stage t+1 before computing t; one barrier/step
        stageB(0, 0);
        stageA_dma(0, 0);
        __syncthreads();
        int cur = 0;
        for (int k0 = 0; k0 < K; k0 += BK) {
            const int nxt = cur ^ 1;
            if (k0 + BK < K) {
                stageB(k0 + BK, nxt % NBUF);
                stageA_dma(k0 + BK, nxt % NBUF);
            }
            compute(cur);
            __syncthreads();
            cur = nxt % NBUF;
        }
    } else {
        // ---- single-buffer with A-register prefetch
        loadA(0);
        for (int k0 = 0; k0 < K; k0 += BK) {
            stageB(k0, 0);   // DMA flies during splitA
            splitA(0);       // consume pv (this step's data)
            __syncthreads();
            if (k0 + BK < K) loadA(k0 + BK);  // latency hides under MFMA phase
            compute(0);
            __syncthreads();
        }
    }
    // ---- epilogue: C/D layout col=l16, row=quad*4+reg; scale by ns, emit fp16
#pragma unroll
    for (int mi = 0; mi < TM; ++mi)
#pragma unroll
        for (int r = 0; r < 4; ++r) {
            int row = m0 + wrow + mi * 16 + quad * 4 + r;
            if (row < M) {
                float s = ns[row];
#pragma unroll
                for (int ni = 0; ni < TN; ++ni) {
                    C[(size_t)row * N + n0 + wcol + ni * 16 + l16] =
                        __float2half(acc[mi][ni][r] * s);
                }
            }
        }
}

// ---------------- gather-row raw load/accumulate helpers (32-lane rows) ------
template <int VEC> struct RawT;
template <> struct RawT<8> { using T = uint4; };
template <> struct RawT<4> { using T = uint2; };
template <> struct RawT<2> { using T = uint_t; };

template <int VEC>
__device__ inline typename RawT<VEC>::T load_raw(const __half* p) {
    return *(const typename RawT<VEC>::T*)p;
}
__device__ inline void add_h2(float* a, uint_t w) {
    __half2 h = *reinterpret_cast<__half2*>(&w);
    float2 f = __half22float2(h);
    a[0] += f.x;
    a[1] += f.y;
}
template <int VEC>
__device__ inline void add_raw(float* a, typename RawT<VEC>::T r) {
    if (VEC == 8) {
        uint4 v = *(uint4*)&r;
        add_h2(a + 0, v.x); add_h2(a + 2, v.y); add_h2(a + 4, v.z); add_h2(a + 6, v.w);
    } else if (VEC == 4) {
        uint2 v = *(uint2*)&r;
        add_h2(a + 0, v.x); add_h2(a + 2, v.y);
    } else {
        uint_t v = *(uint_t*)&r;
        add_h2(a, v);
    }
}
template <int VEC>
__device__ inline void load_add(float* a, const __half* p) {
    add_raw<VEC>(a, load_raw<VEC>(p));
}

// ---------------- CSR aggregation + fused epilogue ----------------
// One node per 32-lane HALF-WAVE; lane covers VEC consecutive cols (dim = 32*VEC).
// res = act(nd[w] * sum_{e: dst==w} tmp[src[e]] + bias)
// OUT_MODE: 0 = fp32 only, 1 = hi/lo planes only, 2 = both
template <int VEC, int RELU, int OUT_MODE>
__global__ void agg_ep_k(const __half* __restrict__ tmp, float* __restrict__ outF,
                         ushort_t* __restrict__ outH, ushort_t* __restrict__ outL,
                         const int* __restrict__ row_start, const int* __restrict__ edge_src,
                         const float* __restrict__ nd, const float* __restrict__ bias,
                         int n_nodes, int dim) {
    int w = (blockIdx.x * blockDim.x + threadIdx.x) >> 5;
    int lane = threadIdx.x & 31;
    if (w >= n_nodes) return;
    int s = row_start[w], e = row_start[w + 1];
    int col = lane * VEC;
    float acc[4][VEC];
#pragma unroll
    for (int c = 0; c < 4; ++c)
#pragma unroll
        for (int j = 0; j < VEC; ++j) acc[c][j] = 0.f;
    int i = s;
    for (; i + 7 < e; i += 8) {
        int u[8];
#pragma unroll
        for (int j = 0; j < 8; ++j) u[j] = edge_src[i + j];
        typename RawT<VEC>::T r[8];
#pragma unroll
        for (int j = 0; j < 8; ++j) r[j] = load_raw<VEC>(tmp + (size_t)u[j] * dim + col);
#pragma unroll
        for (int j = 0; j < 8; ++j) add_raw<VEC>(acc[j & 3], r[j]);
    }
    for (; i + 3 < e; i += 4) {
        int u0 = edge_src[i];
        int u1 = edge_src[i + 1];
        int u2 = edge_src[i + 2];
        int u3 = edge_src[i + 3];
        load_add<VEC>(acc[0], tmp + (size_t)u0 * dim + col);
        load_add<VEC>(acc[1], tmp + (size_t)u1 * dim + col);
        load_add<VEC>(acc[2], tmp + (size_t)u2 * dim + col);
        load_add<VEC>(acc[3], tmp + (size_t)u3 * dim + col);
    }
    for (; i < e; ++i) {
        int u = edge_src[i];
        load_add<VEC>(acc[0], tmp + (size_t)u * dim + col);
    }
    float d = nd[w];
    float r[VEC];
#pragma unroll
    for (int j = 0; j < VEC; ++j) {
        float v = fmaf((acc[0][j] + acc[1][j]) + (acc[2][j] + acc[3][j]), d, bias[col + j]);
        r[j] = RELU ? fmaxf(v, 0.f) : v;
    }
    size_t base = (size_t)w * dim + col;
    if (OUT_MODE != 1) {
        if (VEC == 8) {
            *(float4*)(outF + base) = make_float4(r[0], r[1], r[2], r[3]);
            *(float4*)(outF + base + 4) = make_float4(r[4], r[5], r[6], r[7]);
        } else if (VEC == 4) {
            *(float4*)(outF + base) = make_float4(r[0], r[1], r[2], r[3]);
        } else {
            *(float2*)(outF + base) = make_float2(r[0], r[1]);
        }
    }
    if (OUT_MODE != 0) {
        ushort_t h[VEC], l[VEC];
#pragma unroll
        for (int j = 0; j < VEC; ++j) split1(r[j], h[j], l[j]);
        if (VEC == 8) {
            short8 hv, lv;
#pragma unroll
            for (int j = 0; j < 8; ++j) { hv[j] = (short)h[j]; lv[j] = (short)l[j]; }
            *(short8*)(outH + base) = hv;
            *(short8*)(outL + base) = lv;
        } else if (VEC == 4) {
            *(ushort4*)(outH + base) = make_ushort4(h[0], h[1], h[2], h[3]);
            *(ushort4*)(outL + base) = make_ushort4(l[0], l[1], l[2], l[3]);
        } else {
            *(ushort2*)(outH + base) = make_ushort2(h[0], h[1]);
            *(ushort2*)(outL + base) = make_ushort2(l[0], l[1]);
        }
    }
}

extern "C" void kernel_launch(void* const* d_in, const int* in_sizes, int n_in,
                              void* d_out, int out_size, void* d_ws, size_t ws_size,
                              hipStream_t stream) {
    const float* features = (const float*)d_in[0];
    const int* src = (const int*)d_in[1];
    const int* dst = (const int*)d_in[2];
    const float* W0 = (const float*)d_in[3];
    const float* b0 = (const float*)d_in[4];
    const float* W1 = (const float*)d_in[5];
    const float* b1 = (const float*)d_in[6];
    const float* W2 = (const float*)d_in[7];
    const float* b2 = (const float*)d_in[8];
    const float* W3 = (const float*)d_in[9];
    const float* b3 = (const float*)d_in[10];
    float* out = (float*)d_out;

    // workspace carve (~160 MB)
    char* p = (char*)d_ws;
    auto alloc = [&](size_t bytes) {
        void* r = (void*)p;
        p += (bytes + 255) & ~(size_t)255;
        return r;
    };
    __half* tmp = (__half*)alloc((size_t)N_NODES * 256 * 2);        // 25.6 MB GEMM out (fp16)
    ushort_t* H1hi = (ushort_t*)alloc((size_t)N_NODES * 256 * 2);   // [M][256]
    ushort_t* H1lo = (ushort_t*)alloc((size_t)N_NODES * 256 * 2);
    ushort_t* H2hi = (ushort_t*)alloc((size_t)N_NODES * 256 * 2);   // [M][256]
    ushort_t* H2lo = (ushort_t*)alloc((size_t)N_NODES * 256 * 2);
    ushort_t* H3hi = (ushort_t*)alloc((size_t)N_NODES * 128 * 2);   // [M][128]
    ushort_t* H3lo = (ushort_t*)alloc((size_t)N_NODES * 128 * 2);
    ushort_t* W0hi = (ushort_t*)alloc(512 * 256 * 2);               // Wt planes [N][K]
    ushort_t* W0lo = (ushort_t*)alloc(512 * 256 * 2);
    ushort_t* W1hi = (ushort_t*)alloc(256 * 256 * 2);
    ushort_t* W1lo = (ushort_t*)alloc(256 * 256 * 2);
    ushort_t* W2hi = (ushort_t*)alloc(256 * 128 * 2);
    ushort_t* W2lo = (ushort_t*)alloc(256 * 128 * 2);
    ushort_t* W3hi = (ushort_t*)alloc(128 * 64 * 2);
    ushort_t* W3lo = (ushort_t*)alloc(128 * 64 * 2);
    int* edge_src = (int*)alloc((size_t)N_EDGES * 4);
    int* row_start = (int*)alloc((size_t)(N_NODES + 1) * 4);
    int* degO = (int*)alloc((size_t)N_NODES * 4);
    int* degI = (int*)alloc((size_t)N_NODES * 4);
    int* bsum = (int*)alloc(64 * 4);
    float* ns = (float*)alloc((size_t)N_NODES * 4);
    float* nd = (float*)alloc((size_t)N_NODES * 4);
    // erank aliases tmp: only live between count_deg and fill_csr, before any
    // GEMM writes tmp. 800k ints = 3.2 MB < 25.6 MB.
    int* erank = (int*)tmp;

    // ---- graph preprocessing ----
    hipMemsetAsync(degO, 0, (size_t)N_NODES * 4, stream);
    hipMemsetAsync(degI, 0, (size_t)N_NODES * 4, stream);
    count_deg_k<<<(N_EDGES + 255) / 256, 256, 0, stream>>>(src, dst, N_EDGES, degO, degI, erank);
    norm_k<<<(N_NODES + 255) / 256, 256, 0, stream>>>(degO, degI, ns, nd, N_NODES);
    {
        const int nb = (N_NODES + 1023) / 1024;  // 49
        scan_local_k<<<nb, 1024, 0, stream>>>(degI, row_start, bsum, N_NODES);
        scan_bsum_k<<<1, 64, 0, stream>>>(bsum, row_start + N_NODES, nb);
        scan_add_k<<<(N_NODES + 255) / 256, 256, 0, stream>>>(row_start, bsum, N_NODES);
    }
    fill_csr_k<<<(N_EDGES + 255) / 256, 256, 0, stream>>>(src, dst, N_EDGES, row_start,
                                                          erank, edge_src);

    // ---- weight splits (one launch) ----
    {
        const int tot = 512 * 256 + 256 * 256 + 256 * 128 + 128 * 64;
        split_weights_k<<<(tot + 255) / 256, 256, 0, stream>>>(
            W0, W1, W2, W3, W0hi, W0lo, W1hi, W1lo, W2hi, W2lo, W3hi, W3lo);
    }

    const int gm = (N_NODES + 127) / 128;     // 391 blocks, BM=128
    const int aggBlocks = (N_NODES + 7) / 8;  // 8 nodes/block (32-lane halves)

    // ---- layer 0: 512 -> 256 (feature split fused into staging, single-buf) ----
    gemm_mfma_k<128, 1><<<dim3(gm, 2), 256, 0, stream>>>(features, nullptr, nullptr,
                                                         W0hi, W0lo, tmp, N_NODES, 512, 256, ns);
    agg_ep_k<8, 1, 1><<<aggBlocks, 256, 0, stream>>>(tmp, nullptr, H1hi, H1lo, row_start,
                                                     edge_src, nd, b0, N_NODES, 256);

    // ---- layer 1: 256 -> 256 (dbuf DMA pipeline) ----
    gemm_mfma_k<128, 0><<<dim3(gm, 2), 256, 0, stream>>>(nullptr, H1hi, H1lo, W1hi, W1lo,
                                                         tmp, N_NODES, 256, 256, ns);
    agg_ep_k<8, 1, 1><<<aggBlocks, 256, 0, stream>>>(tmp, nullptr, H2hi, H2lo, row_start,
                                                     edge_src, nd, b1, N_NODES, 256);

    // ---- layer 2: 256 -> 128 (aspect_embed -> d_out, planes for L3) ----
    gemm_mfma_k<128, 0><<<dim3(gm, 1), 256, 0, stream>>>(nullptr, H2hi, H2lo, W2hi, W2lo,
                                                         tmp, N_NODES, 256, 128, ns);
    agg_ep_k<4, 0, 2><<<aggBlocks, 256, 0, stream>>>(tmp, out, H3hi, H3lo, row_start,
                                                     edge_src, nd, b2, N_NODES, 128);

    // ---- layer 3: 128 -> 64 (h -> d_out + 50000*128) ----
    gemm_mfma_k<64, 0><<<dim3(gm, 1), 256, 0, stream>>>(nullptr, H3hi, H3lo, W3hi, W3lo,
                                                        tmp, N_NODES, 128, 64, ns);
    agg_ep_k<2, 0, 0><<<aggBlocks, 256, 0, stream>>>(tmp, out + (size_t)N_NODES * 128,
                                                     nullptr, nullptr, row_start, edge_src,
                                                     nd, b3, N_NODES, 64);
}